// Round 1
// baseline (5693.147 us; speedup 1.0000x reference)
//
#include <hip/hip_runtime.h>
#include <math.h>

constexpr int H = 64;
constexpr int FIN = 128;

// ---------------- degree / dinv ----------------
__global__ void k_deg(const int* __restrict__ dst, int E, int* __restrict__ cnt) {
    int e = blockIdx.x * blockDim.x + threadIdx.x;
    if (e < E) atomicAdd(&cnt[dst[e]], 1);
}

__global__ void k_dinv(const int* __restrict__ cnt, int N, float* __restrict__ dinv) {
    int i = blockIdx.x * blockDim.x + threadIdx.x;
    if (i < N) dinv[i] = 1.0f / sqrtf((float)cnt[i] + 1.0f);  // +1 self-loop
}

// ---------------- GEMM1: h1 = x @ W1 ; A = h1*dinv ; B = h1*dinv^2 (self-loop init) ----------------
__global__ __launch_bounds__(256) void k_gemm1(
    const float* __restrict__ x, const float* __restrict__ W1,
    const float* __restrict__ dinv, int N,
    float* __restrict__ A, float* __restrict__ B) {
    __shared__ float sW[FIN * H];      // 32 KB
    __shared__ float sx[16][FIN];      // 8 KB
    int tid = threadIdx.x;
    for (int i = tid; i < FIN * H; i += 256) sW[i] = W1[i];
    int row0 = blockIdx.x * 16;
    for (int i = tid; i < 16 * (FIN / 4); i += 256) {
        int r = i / (FIN / 4), c = i % (FIN / 4);
        int row = row0 + r;
        float4 v = make_float4(0.f, 0.f, 0.f, 0.f);
        if (row < N) v = ((const float4*)(x + (size_t)row * FIN))[c];
        ((float4*)&sx[r][0])[c] = v;
    }
    __syncthreads();
    int col = tid & 63;
    int r0 = (tid >> 6) * 4;           // 4 rows per thread
    float acc[4] = {0.f, 0.f, 0.f, 0.f};
    for (int k = 0; k < FIN; ++k) {
        float w = sW[k * H + col];
#pragma unroll
        for (int r = 0; r < 4; ++r) acc[r] += sx[r0 + r][k] * w;
    }
#pragma unroll
    for (int r = 0; r < 4; ++r) {
        int row = row0 + r0 + r;
        if (row < N) {
            float dv = dinv[row];
            float h = acc[r];
            A[(size_t)row * H + col] = h * dv;
            B[(size_t)row * H + col] = h * dv * dv;
        }
    }
}

// ---------------- GEMM2: g = relu(B + b1); h2 = g @ W2 ; A = h2*dinv ; B = h2*dinv^2 ----------------
__global__ __launch_bounds__(256) void k_gemm2(
    const float* __restrict__ W2, const float* __restrict__ b1,
    const float* __restrict__ dinv, int N,
    float* __restrict__ A, float* __restrict__ B) {
    __shared__ float sW[H * H];        // 16 KB
    __shared__ float sh[16][H];        // 4 KB
    int tid = threadIdx.x;
    for (int i = tid; i < H * H; i += 256) sW[i] = W2[i];
    int row0 = blockIdx.x * 16;
    for (int i = tid; i < 16 * H; i += 256) {
        int r = i / H, c = i % H;
        int row = row0 + r;
        float v = 0.f;
        if (row < N) v = B[(size_t)row * H + c] + b1[c];
        sh[r][c] = fmaxf(v, 0.f);
    }
    __syncthreads();
    int col = tid & 63;
    int r0 = (tid >> 6) * 4;
    float acc[4] = {0.f, 0.f, 0.f, 0.f};
    for (int k = 0; k < H; ++k) {
        float w = sW[k * H + col];
#pragma unroll
        for (int r = 0; r < 4; ++r) acc[r] += sh[r0 + r][k] * w;
    }
#pragma unroll
    for (int r = 0; r < 4; ++r) {
        int row = row0 + r0 + r;
        if (row < N) {
            float dv = dinv[row];
            A[(size_t)row * H + col] = acc[r] * dv;
            B[(size_t)row * H + col] = acc[r] * dv * dv;
        }
    }
}

// ---------------- edge scatter: B[dst] += A[src] * dinv[dst] ----------------
__global__ __launch_bounds__(256) void k_scatter(
    const int* __restrict__ src, const int* __restrict__ dst, int E,
    const float* __restrict__ dinv,
    const float* __restrict__ A, float* __restrict__ B) {
    int t = blockIdx.x * blockDim.x + threadIdx.x;
    int e = t >> 4;                    // 16 lanes per edge (float4 each)
    if (e >= E) return;
    int l = t & 15;
    int s = src[e], d = dst[e];
    float dv = dinv[d];
    float4 v = ((const float4*)(A + (size_t)s * H))[l];
    float* out = (float*)(B + (size_t)d * H) + l * 4;
    unsafeAtomicAdd(out + 0, v.x * dv);
    unsafeAtomicAdd(out + 1, v.y * dv);
    unsafeAtomicAdd(out + 2, v.z * dv);
    unsafeAtomicAdd(out + 3, v.w * dv);
}

// ---------------- heads: g = relu(B + b2); out = [g@Wt + bt ; g@We + be] ----------------
__global__ __launch_bounds__(256) void k_heads(
    const float* __restrict__ B, const float* __restrict__ b2,
    const float* __restrict__ Wt, const float* __restrict__ bt,
    const float* __restrict__ We, const float* __restrict__ be,
    int N, float* __restrict__ out) {
    int t = blockIdx.x * blockDim.x + threadIdx.x;
    int node = t >> 6;
    int lane = t & 63;
    if (node >= N) return;
    float g = fmaxf(B[(size_t)node * H + lane] + b2[lane], 0.f);
    float p1 = g * Wt[lane];
    float p2 = g * We[lane];
#pragma unroll
    for (int off = 32; off; off >>= 1) {
        p1 += __shfl_down(p1, off);
        p2 += __shfl_down(p2, off);
    }
    if (lane == 0) {
        out[node] = p1 + bt[0];
        out[N + node] = p2 + be[0];
    }
}

extern "C" void kernel_launch(void* const* d_in, const int* in_sizes, int n_in,
                              void* d_out, int out_size, void* d_ws, size_t ws_size,
                              hipStream_t stream) {
    const float* x  = (const float*)d_in[0];
    const int* edge = (const int*)d_in[1];
    const float* W1 = (const float*)d_in[2];
    const float* b1 = (const float*)d_in[3];
    const float* W2 = (const float*)d_in[4];
    const float* b2 = (const float*)d_in[5];
    const float* Wt = (const float*)d_in[6];
    const float* bt = (const float*)d_in[7];
    const float* We = (const float*)d_in[8];
    const float* be = (const float*)d_in[9];

    int N = in_sizes[0] / FIN;
    int E = in_sizes[1] / 2;
    const int* src = edge;
    const int* dst = edge + E;

    char* ws = (char*)d_ws;
    size_t off = 0;
    auto alloc = [&](size_t bytes) {
        void* p = ws + off;
        off += (bytes + 255) & ~size_t(255);
        return p;
    };
    int*   cnt  = (int*)alloc((size_t)N * sizeof(int));
    float* dinv = (float*)alloc((size_t)N * sizeof(float));
    float* A    = (float*)alloc((size_t)N * H * sizeof(float));
    float* B    = (float*)alloc((size_t)N * H * sizeof(float));

    hipMemsetAsync(cnt, 0, (size_t)N * sizeof(int), stream);
    k_deg<<<(E + 255) / 256, 256, 0, stream>>>(dst, E, cnt);
    k_dinv<<<(N + 255) / 256, 256, 0, stream>>>(cnt, N, dinv);

    // layer 1
    k_gemm1<<<(N + 15) / 16, 256, 0, stream>>>(x, W1, dinv, N, A, B);
    {
        long long threads = (long long)E * 16;
        k_scatter<<<(int)((threads + 255) / 256), 256, 0, stream>>>(src, dst, E, dinv, A, B);
    }

    // layer 2 (relu + bias of layer1 fused into GEMM2 input load)
    k_gemm2<<<(N + 15) / 16, 256, 0, stream>>>(W2, b1, dinv, N, A, B);
    {
        long long threads = (long long)E * 16;
        k_scatter<<<(int)((threads + 255) / 256), 256, 0, stream>>>(src, dst, E, dinv, A, B);
    }

    // heads
    {
        long long threads = (long long)N * 64;
        k_heads<<<(int)((threads + 255) / 256), 256, 0, stream>>>(B, b2, Wt, bt, We, be, N, (float*)d_out);
    }
}

// Round 2
// 766.346 us; speedup vs baseline: 7.4290x; 7.4290x over previous
//
#include <hip/hip_runtime.h>
#include <math.h>

constexpr int H = 64;
constexpr int FIN = 128;

// ---------------- degree ----------------
__global__ void k_deg(const int* __restrict__ dst, int E, int* __restrict__ cnt) {
    int e = blockIdx.x * blockDim.x + threadIdx.x;
    if (e < E) atomicAdd(&cnt[dst[e]], 1);
}

__global__ void k_dinv(const int* __restrict__ cnt, int N, float* __restrict__ dinv) {
    int i = blockIdx.x * blockDim.x + threadIdx.x;
    if (i < N) dinv[i] = 1.0f / sqrtf((float)cnt[i] + 1.0f);  // +1 self-loop
}

// ---------------- exclusive scan (rowptr) ----------------
__device__ inline int wave_incl_scan(int v, int lane) {
#pragma unroll
    for (int off = 1; off < 64; off <<= 1) {
        int t = __shfl_up(v, off);
        if (lane >= off) v += t;
    }
    return v;
}

// each block scans 1024 elements (4/thread); local exclusive scan + block sum
__global__ __launch_bounds__(256) void k_scan1(const int* __restrict__ cnt, int N,
                                               int* __restrict__ rowptr, int* __restrict__ blockSum) {
    __shared__ int wsum[4];
    int tid = threadIdx.x, lane = tid & 63, wid = tid >> 6;
    int base = blockIdx.x * 1024 + tid * 4;
    int c[4];
#pragma unroll
    for (int k = 0; k < 4; ++k) c[k] = (base + k < N) ? cnt[base + k] : 0;
    int t = c[0] + c[1] + c[2] + c[3];
    int incl = wave_incl_scan(t, lane);
    if (lane == 63) wsum[wid] = incl;
    __syncthreads();
    int woff = 0;
    for (int w = 0; w < wid; ++w) woff += wsum[w];
    int p = woff + incl - t;
#pragma unroll
    for (int k = 0; k < 4; ++k) {
        if (base + k < N) rowptr[base + k] = p;
        p += c[k];
    }
    if (tid == 255) blockSum[blockIdx.x] = woff + incl;
}

// single block: exclusive scan of blockSum[nb], nb <= 256
__global__ __launch_bounds__(256) void k_scan2(int* __restrict__ blockSum, int nb) {
    __shared__ int wsum[4];
    int tid = threadIdx.x, lane = tid & 63, wid = tid >> 6;
    int v = (tid < nb) ? blockSum[tid] : 0;
    int incl = wave_incl_scan(v, lane);
    if (lane == 63) wsum[wid] = incl;
    __syncthreads();
    int woff = 0;
    for (int w = 0; w < wid; ++w) woff += wsum[w];
    if (tid < nb) blockSum[tid] = woff + incl - v;
}

__global__ void k_scan3(int* __restrict__ rowptr, const int* __restrict__ blockSum, int N, int E) {
    int i = blockIdx.x * blockDim.x + threadIdx.x;
    if (i < N) rowptr[i] += blockSum[i >> 10];
    if (i == 0) rowptr[N] = E;
}

// ---------------- CSR fill: csr_src grouped by dst ----------------
__global__ void k_fill(const int* __restrict__ src, const int* __restrict__ dst, int E,
                       const int* __restrict__ rowptr, int* __restrict__ cnt,
                       int* __restrict__ csr_src) {
    int e = blockIdx.x * blockDim.x + threadIdx.x;
    if (e >= E) return;
    int d = dst[e];
    int c = atomicSub(&cnt[d], 1) - 1;   // reuse cnt as fill cursor (ends at 0)
    csr_src[rowptr[d] + c] = src[e];
}

// ---------------- GEMM1: A = (x @ W1) * dinv ----------------
__global__ __launch_bounds__(256) void k_gemm1(
    const float* __restrict__ x, const float* __restrict__ W1,
    const float* __restrict__ dinv, int N, float* __restrict__ A) {
    __shared__ float sW[FIN * H];      // 32 KB
    __shared__ float sx[16][FIN];      // 8 KB
    int tid = threadIdx.x;
    for (int i = tid; i < FIN * H; i += 256) sW[i] = W1[i];
    int row0 = blockIdx.x * 16;
    for (int i = tid; i < 16 * (FIN / 4); i += 256) {
        int r = i / (FIN / 4), c = i % (FIN / 4);
        int row = row0 + r;
        float4 v = make_float4(0.f, 0.f, 0.f, 0.f);
        if (row < N) v = ((const float4*)(x + (size_t)row * FIN))[c];
        ((float4*)&sx[r][0])[c] = v;
    }
    __syncthreads();
    int col = tid & 63;
    int r0 = (tid >> 6) * 4;
    float acc[4] = {0.f, 0.f, 0.f, 0.f};
    for (int k = 0; k < FIN; ++k) {
        float w = sW[k * H + col];
#pragma unroll
        for (int r = 0; r < 4; ++r) acc[r] += sx[r0 + r][k] * w;
    }
#pragma unroll
    for (int r = 0; r < 4; ++r) {
        int row = row0 + r0 + r;
        if (row < N) A[(size_t)row * H + col] = acc[r] * dinv[row];
    }
}

// ---------------- GEMM2: g = relu(B + b1); A = (g @ W2) * dinv ----------------
__global__ __launch_bounds__(256) void k_gemm2(
    const float* __restrict__ B, const float* __restrict__ W2, const float* __restrict__ b1,
    const float* __restrict__ dinv, int N, float* __restrict__ A) {
    __shared__ float sW[H * H];        // 16 KB
    __shared__ float sh[16][H];        // 4 KB
    int tid = threadIdx.x;
    for (int i = tid; i < H * H; i += 256) sW[i] = W2[i];
    int row0 = blockIdx.x * 16;
    for (int i = tid; i < 16 * H; i += 256) {
        int r = i / H, c = i % H;
        int row = row0 + r;
        float v = 0.f;
        if (row < N) v = B[(size_t)row * H + c] + b1[c];
        sh[r][c] = fmaxf(v, 0.f);
    }
    __syncthreads();
    int col = tid & 63;
    int r0 = (tid >> 6) * 4;
    float acc[4] = {0.f, 0.f, 0.f, 0.f};
    for (int k = 0; k < H; ++k) {
        float w = sW[k * H + col];
#pragma unroll
        for (int r = 0; r < 4; ++r) acc[r] += sh[r0 + r][k] * w;
    }
#pragma unroll
    for (int r = 0; r < 4; ++r) {
        int row = row0 + r0 + r;
        if (row < N) A[(size_t)row * H + col] = acc[r] * dinv[row];
    }
}

// ---------------- gather: B[n] = dinv[n] * (A[n] + sum_{s in in(n)} A[s]) ----------------
__global__ __launch_bounds__(256) void k_gather(
    const int* __restrict__ rowptr, const int* __restrict__ csr_src,
    const float* __restrict__ dinv, const float* __restrict__ A,
    float* __restrict__ B, int N) {
    int node = blockIdx.x * 4 + (threadIdx.x >> 6);
    if (node >= N) return;
    int lane = threadIdx.x & 63;
    int beg = rowptr[node], end = rowptr[node + 1];
    float acc0 = A[(size_t)node * H + lane];   // self-loop: h*dinv -> *dinv below
    float acc1 = 0.f, acc2 = 0.f, acc3 = 0.f;
    for (int e0 = beg; e0 < end; e0 += 64) {
        int m = end - e0; if (m > 64) m = 64;
        int id = (lane < m) ? csr_src[e0 + lane] : 0;
        int j = 0;
        for (; j + 4 <= m; j += 4) {
            int s0 = __builtin_amdgcn_readlane(id, j);
            int s1 = __builtin_amdgcn_readlane(id, j + 1);
            int s2 = __builtin_amdgcn_readlane(id, j + 2);
            int s3 = __builtin_amdgcn_readlane(id, j + 3);
            float b0 = A[(size_t)s0 * H + lane];
            float b1 = A[(size_t)s1 * H + lane];
            float b2 = A[(size_t)s2 * H + lane];
            float b3 = A[(size_t)s3 * H + lane];
            acc0 += b0; acc1 += b1; acc2 += b2; acc3 += b3;
        }
        for (; j < m; ++j) {
            int s = __builtin_amdgcn_readlane(id, j);
            acc0 += A[(size_t)s * H + lane];
        }
    }
    B[(size_t)node * H + lane] = (acc0 + acc1 + acc2 + acc3) * dinv[node];
}

// ---------------- heads ----------------
__global__ __launch_bounds__(256) void k_heads(
    const float* __restrict__ B, const float* __restrict__ b2,
    const float* __restrict__ Wt, const float* __restrict__ bt,
    const float* __restrict__ We, const float* __restrict__ be,
    int N, float* __restrict__ out) {
    int t = blockIdx.x * blockDim.x + threadIdx.x;
    int node = t >> 6;
    int lane = t & 63;
    if (node >= N) return;
    float g = fmaxf(B[(size_t)node * H + lane] + b2[lane], 0.f);
    float p1 = g * Wt[lane];
    float p2 = g * We[lane];
#pragma unroll
    for (int off = 32; off; off >>= 1) {
        p1 += __shfl_down(p1, off);
        p2 += __shfl_down(p2, off);
    }
    if (lane == 0) {
        out[node] = p1 + bt[0];
        out[N + node] = p2 + be[0];
    }
}

extern "C" void kernel_launch(void* const* d_in, const int* in_sizes, int n_in,
                              void* d_out, int out_size, void* d_ws, size_t ws_size,
                              hipStream_t stream) {
    const float* x  = (const float*)d_in[0];
    const int* edge = (const int*)d_in[1];
    const float* W1 = (const float*)d_in[2];
    const float* b1 = (const float*)d_in[3];
    const float* W2 = (const float*)d_in[4];
    const float* b2 = (const float*)d_in[5];
    const float* Wt = (const float*)d_in[6];
    const float* bt = (const float*)d_in[7];
    const float* We = (const float*)d_in[8];
    const float* be = (const float*)d_in[9];

    int N = in_sizes[0] / FIN;
    int E = in_sizes[1] / 2;
    const int* src = edge;
    const int* dst = edge + E;

    char* ws = (char*)d_ws;
    size_t off = 0;
    auto alloc = [&](size_t bytes) {
        void* p = ws + off;
        off += (bytes + 255) & ~size_t(255);
        return p;
    };
    int*   cnt      = (int*)alloc((size_t)N * sizeof(int));
    float* dinv     = (float*)alloc((size_t)N * sizeof(float));
    int*   rowptr   = (int*)alloc((size_t)(N + 1) * sizeof(int));
    int*   blockSum = (int*)alloc(256 * sizeof(int));
    int*   csr_src  = (int*)alloc((size_t)E * sizeof(int));
    float* A        = (float*)alloc((size_t)N * H * sizeof(float));
    float* B        = (float*)alloc((size_t)N * H * sizeof(float));

    int nb = (N + 1023) / 1024;   // scan blocks (<=256 supported)

    hipMemsetAsync(cnt, 0, (size_t)N * sizeof(int), stream);
    k_deg<<<(E + 255) / 256, 256, 0, stream>>>(dst, E, cnt);
    k_dinv<<<(N + 255) / 256, 256, 0, stream>>>(cnt, N, dinv);

    // CSR build (by dst)
    k_scan1<<<nb, 256, 0, stream>>>(cnt, N, rowptr, blockSum);
    k_scan2<<<1, 256, 0, stream>>>(blockSum, nb);
    k_scan3<<<(N + 255) / 256, 256, 0, stream>>>(rowptr, blockSum, N, E);
    k_fill<<<(E + 255) / 256, 256, 0, stream>>>(src, dst, E, rowptr, cnt, csr_src);

    // layer 1
    k_gemm1<<<(N + 15) / 16, 256, 0, stream>>>(x, W1, dinv, N, A);
    k_gather<<<(N + 3) / 4, 256, 0, stream>>>(rowptr, csr_src, dinv, A, B, N);

    // layer 2
    k_gemm2<<<(N + 15) / 16, 256, 0, stream>>>(B, W2, b1, dinv, N, A);
    k_gather<<<(N + 3) / 4, 256, 0, stream>>>(rowptr, csr_src, dinv, A, B, N);

    // heads
    {
        long long threads = (long long)N * 64;
        k_heads<<<(int)((threads + 255) / 256), 256, 0, stream>>>(B, b2, Wt, bt, We, be, N, (float*)d_out);
    }
}

// Round 3
// 705.117 us; speedup vs baseline: 8.0740x; 1.0868x over previous
//
#include <hip/hip_runtime.h>
#include <math.h>

constexpr int H = 64;
constexpr int FIN = 128;
constexpr int NSWEEP = 8;

// ---------------- degree ----------------
__global__ void k_deg(const int* __restrict__ dst, int E, int* __restrict__ cnt) {
    int e = blockIdx.x * blockDim.x + threadIdx.x;
    if (e < E) atomicAdd(&cnt[dst[e]], 1);
}

__global__ void k_dinv(const int* __restrict__ cnt, int N, float* __restrict__ dinv) {
    int i = blockIdx.x * blockDim.x + threadIdx.x;
    if (i < N) dinv[i] = 1.0f / sqrtf((float)cnt[i] + 1.0f);  // +1 self-loop
}

// ---------------- exclusive scan (rowptr) ----------------
__device__ inline int wave_incl_scan(int v, int lane) {
#pragma unroll
    for (int off = 1; off < 64; off <<= 1) {
        int t = __shfl_up(v, off);
        if (lane >= off) v += t;
    }
    return v;
}

__global__ __launch_bounds__(256) void k_scan1(const int* __restrict__ cnt, int N,
                                               int* __restrict__ rowptr, int* __restrict__ blockSum) {
    __shared__ int wsum[4];
    int tid = threadIdx.x, lane = tid & 63, wid = tid >> 6;
    int base = blockIdx.x * 1024 + tid * 4;
    int c[4];
#pragma unroll
    for (int k = 0; k < 4; ++k) c[k] = (base + k < N) ? cnt[base + k] : 0;
    int t = c[0] + c[1] + c[2] + c[3];
    int incl = wave_incl_scan(t, lane);
    if (lane == 63) wsum[wid] = incl;
    __syncthreads();
    int woff = 0;
    for (int w = 0; w < wid; ++w) woff += wsum[w];
    int p = woff + incl - t;
#pragma unroll
    for (int k = 0; k < 4; ++k) {
        if (base + k < N) rowptr[base + k] = p;
        p += c[k];
    }
    if (tid == 255) blockSum[blockIdx.x] = woff + incl;
}

__global__ __launch_bounds__(256) void k_scan2(int* __restrict__ blockSum, int nb) {
    __shared__ int wsum[4];
    int tid = threadIdx.x, lane = tid & 63, wid = tid >> 6;
    int v = (tid < nb) ? blockSum[tid] : 0;
    int incl = wave_incl_scan(v, lane);
    if (lane == 63) wsum[wid] = incl;
    __syncthreads();
    int woff = 0;
    for (int w = 0; w < wid; ++w) woff += wsum[w];
    if (tid < nb) blockSum[tid] = woff + incl - v;
}

__global__ void k_scan3(int* __restrict__ rowptr, const int* __restrict__ blockSum, int N, int E) {
    int i = blockIdx.x * blockDim.x + threadIdx.x;
    if (i < N) rowptr[i] += blockSum[i >> 10];
    if (i == 0) rowptr[N] = E;
}

// ---------------- CSR fill, dst-range sweep for L2-local writes ----------------
__global__ void k_fill(const int* __restrict__ src, const int* __restrict__ dst, int E,
                       const int* __restrict__ rowptr, int* __restrict__ cnt,
                       int* __restrict__ csr_src, int lo, int hi) {
    int e = blockIdx.x * blockDim.x + threadIdx.x;
    if (e >= E) return;
    int d = dst[e];
    if (d < lo || d >= hi) return;
    int c = atomicSub(&cnt[d], 1) - 1;   // cnt ends at 0 for all nodes after last sweep
    csr_src[rowptr[d] + c] = src[e];
}

// ---------------- GEMM1: A = (x @ W1) * dinv ----------------
__global__ __launch_bounds__(256) void k_gemm1(
    const float* __restrict__ x, const float* __restrict__ W1,
    const float* __restrict__ dinv, int N, float* __restrict__ A) {
    __shared__ float sW[FIN * H];      // 32 KB
    __shared__ float sx[16][FIN];      // 8 KB
    int tid = threadIdx.x;
    for (int i = tid; i < FIN * H; i += 256) sW[i] = W1[i];
    int row0 = blockIdx.x * 16;
    for (int i = tid; i < 16 * (FIN / 4); i += 256) {
        int r = i / (FIN / 4), c = i % (FIN / 4);
        int row = row0 + r;
        float4 v = make_float4(0.f, 0.f, 0.f, 0.f);
        if (row < N) v = ((const float4*)(x + (size_t)row * FIN))[c];
        ((float4*)&sx[r][0])[c] = v;
    }
    __syncthreads();
    int col = tid & 63;
    int r0 = (tid >> 6) * 4;
    float acc[4] = {0.f, 0.f, 0.f, 0.f};
    for (int k = 0; k < FIN; ++k) {
        float w = sW[k * H + col];
#pragma unroll
        for (int r = 0; r < 4; ++r) acc[r] += sx[r0 + r][k] * w;
    }
#pragma unroll
    for (int r = 0; r < 4; ++r) {
        int row = row0 + r0 + r;
        if (row < N) A[(size_t)row * H + col] = acc[r] * dinv[row];
    }
}

// ---------------- GEMM2: g = relu(B + b1); A = (g @ W2) * dinv ----------------
__global__ __launch_bounds__(256) void k_gemm2(
    const float* __restrict__ B, const float* __restrict__ W2, const float* __restrict__ b1,
    const float* __restrict__ dinv, int N, float* __restrict__ A) {
    __shared__ float sW[H * H];        // 16 KB
    __shared__ float sh[16][H];        // 4 KB
    int tid = threadIdx.x;
    for (int i = tid; i < H * H; i += 256) sW[i] = W2[i];
    int row0 = blockIdx.x * 16;
    for (int i = tid; i < 16 * H; i += 256) {
        int r = i / H, c = i % H;
        int row = row0 + r;
        float v = 0.f;
        if (row < N) v = B[(size_t)row * H + c] + b1[c];
        sh[r][c] = fmaxf(v, 0.f);
    }
    __syncthreads();
    int col = tid & 63;
    int r0 = (tid >> 6) * 4;
    float acc[4] = {0.f, 0.f, 0.f, 0.f};
    for (int k = 0; k < H; ++k) {
        float w = sW[k * H + col];
#pragma unroll
        for (int r = 0; r < 4; ++r) acc[r] += sh[r0 + r][k] * w;
    }
#pragma unroll
    for (int r = 0; r < 4; ++r) {
        int row = row0 + r0 + r;
        if (row < N) A[(size_t)row * H + col] = acc[r] * dinv[row];
    }
}

// ---------------- gather: B[n] = dinv[n] * (A[n] + sum_{s in in(n)} A[s]) ----------------
// one wave per node; 4 groups of 16 lanes; float4 per lane (16 lanes cover a 64-f row)
__device__ inline void add4(float4& a, const float4& b) {
    a.x += b.x; a.y += b.y; a.z += b.z; a.w += b.w;
}

__global__ __launch_bounds__(256) void k_gather(
    const int* __restrict__ rowptr, const int* __restrict__ csr_src,
    const float* __restrict__ dinv, const float* __restrict__ A,
    float* __restrict__ B, int N) {
    int node = blockIdx.x * 4 + (threadIdx.x >> 6);
    if (node >= N) return;
    int lane = threadIdx.x & 63;
    int grp = lane >> 4, sub = lane & 15;
    const float4* A4 = (const float4*)A;
    int beg = rowptr[node], end = rowptr[node + 1];
    float4 a0 = make_float4(0.f, 0.f, 0.f, 0.f), a1 = a0, a2 = a0, a3 = a0;
    if (grp == 0) a0 = A4[(size_t)node * 16 + sub];   // self-loop term
    for (int e0 = beg; e0 < end; e0 += 64) {
        int m = end - e0; if (m > 64) m = 64;
        int id = (lane < m) ? csr_src[e0 + lane] : 0;
        int c = 0;
        for (; c + 16 <= m; c += 16) {
            int s0 = __shfl(id, c + grp);
            int s1 = __shfl(id, c + 4 + grp);
            int s2 = __shfl(id, c + 8 + grp);
            int s3 = __shfl(id, c + 12 + grp);
            float4 v0 = A4[(size_t)s0 * 16 + sub];
            float4 v1 = A4[(size_t)s1 * 16 + sub];
            float4 v2 = A4[(size_t)s2 * 16 + sub];
            float4 v3 = A4[(size_t)s3 * 16 + sub];
            add4(a0, v0); add4(a1, v1); add4(a2, v2); add4(a3, v3);
        }
        for (; c < m; c += 4) {
            int cc = c + grp;
            int s = __shfl(id, cc < m ? cc : 0);
            if (cc < m) { float4 v = A4[(size_t)s * 16 + sub]; add4(a0, v); }
        }
    }
    add4(a0, a1); add4(a2, a3); add4(a0, a2);
    a0.x += __shfl_xor(a0.x, 16); a0.y += __shfl_xor(a0.y, 16);
    a0.z += __shfl_xor(a0.z, 16); a0.w += __shfl_xor(a0.w, 16);
    a0.x += __shfl_xor(a0.x, 32); a0.y += __shfl_xor(a0.y, 32);
    a0.z += __shfl_xor(a0.z, 32); a0.w += __shfl_xor(a0.w, 32);
    if (grp == 0) {
        float dv = dinv[node];
        a0.x *= dv; a0.y *= dv; a0.z *= dv; a0.w *= dv;
        ((float4*)B)[(size_t)node * 16 + sub] = a0;
    }
}

// ---------------- heads ----------------
__global__ __launch_bounds__(256) void k_heads(
    const float* __restrict__ B, const float* __restrict__ b2,
    const float* __restrict__ Wt, const float* __restrict__ bt,
    const float* __restrict__ We, const float* __restrict__ be,
    int N, float* __restrict__ out) {
    int t = blockIdx.x * blockDim.x + threadIdx.x;
    int node = t >> 6;
    int lane = t & 63;
    if (node >= N) return;
    float g = fmaxf(B[(size_t)node * H + lane] + b2[lane], 0.f);
    float p1 = g * Wt[lane];
    float p2 = g * We[lane];
#pragma unroll
    for (int off = 32; off; off >>= 1) {
        p1 += __shfl_down(p1, off);
        p2 += __shfl_down(p2, off);
    }
    if (lane == 0) {
        out[node] = p1 + bt[0];
        out[N + node] = p2 + be[0];
    }
}

extern "C" void kernel_launch(void* const* d_in, const int* in_sizes, int n_in,
                              void* d_out, int out_size, void* d_ws, size_t ws_size,
                              hipStream_t stream) {
    const float* x  = (const float*)d_in[0];
    const int* edge = (const int*)d_in[1];
    const float* W1 = (const float*)d_in[2];
    const float* b1 = (const float*)d_in[3];
    const float* W2 = (const float*)d_in[4];
    const float* b2 = (const float*)d_in[5];
    const float* Wt = (const float*)d_in[6];
    const float* bt = (const float*)d_in[7];
    const float* We = (const float*)d_in[8];
    const float* be = (const float*)d_in[9];

    int N = in_sizes[0] / FIN;
    int E = in_sizes[1] / 2;
    const int* src = edge;
    const int* dst = edge + E;

    char* ws = (char*)d_ws;
    size_t off = 0;
    auto alloc = [&](size_t bytes) {
        void* p = ws + off;
        off += (bytes + 255) & ~size_t(255);
        return p;
    };
    int*   cnt      = (int*)alloc((size_t)N * sizeof(int));
    float* dinv     = (float*)alloc((size_t)N * sizeof(float));
    int*   rowptr   = (int*)alloc((size_t)(N + 1) * sizeof(int));
    int*   blockSum = (int*)alloc(256 * sizeof(int));
    int*   csr_src  = (int*)alloc((size_t)E * sizeof(int));
    float* A        = (float*)alloc((size_t)N * H * sizeof(float));
    float* B        = (float*)alloc((size_t)N * H * sizeof(float));

    int nb = (N + 1023) / 1024;

    hipMemsetAsync(cnt, 0, (size_t)N * sizeof(int), stream);
    k_deg<<<(E + 255) / 256, 256, 0, stream>>>(dst, E, cnt);
    k_dinv<<<(N + 255) / 256, 256, 0, stream>>>(cnt, N, dinv);

    // CSR build (by dst), sweep fill for L2-local csr writes
    k_scan1<<<nb, 256, 0, stream>>>(cnt, N, rowptr, blockSum);
    k_scan2<<<1, 256, 0, stream>>>(blockSum, nb);
    k_scan3<<<(N + 255) / 256, 256, 0, stream>>>(rowptr, blockSum, N, E);
    {
        int range = (N + NSWEEP - 1) / NSWEEP;
        for (int s = 0; s < NSWEEP; ++s) {
            int lo = s * range;
            int hi = lo + range; if (hi > N) hi = N;
            if (lo >= hi) break;
            k_fill<<<(E + 255) / 256, 256, 0, stream>>>(src, dst, E, rowptr, cnt, csr_src, lo, hi);
        }
    }

    // layer 1
    k_gemm1<<<(N + 15) / 16, 256, 0, stream>>>(x, W1, dinv, N, A);
    k_gather<<<(N + 3) / 4, 256, 0, stream>>>(rowptr, csr_src, dinv, A, B, N);

    // layer 2
    k_gemm2<<<(N + 15) / 16, 256, 0, stream>>>(B, W2, b1, dinv, N, A);
    k_gather<<<(N + 3) / 4, 256, 0, stream>>>(rowptr, csr_src, dinv, A, B, N);

    // heads
    {
        long long threads = (long long)N * 64;
        k_heads<<<(int)((threads + 255) / 256), 256, 0, stream>>>(B, b2, Wt, bt, We, be, N, (float*)d_out);
    }
}

// Round 4
// 565.111 us; speedup vs baseline: 10.0744x; 1.2477x over previous
//
#include <hip/hip_runtime.h>
#include <math.h>

constexpr int H = 64;
constexpr int FIN = 128;
constexpr int NSWEEP = 4;

// ---------------- degree + rank: rank[e] = arrival index of e at its dst ----------------
__global__ void k_deg_rank(const int* __restrict__ dst, int E,
                           int* __restrict__ cnt, int* __restrict__ rank) {
    int e = blockIdx.x * blockDim.x + threadIdx.x;
    if (e < E) rank[e] = atomicAdd(&cnt[dst[e]], 1);
}

// ---------------- exclusive scan (rowptr) + dinv ----------------
__device__ inline int wave_incl_scan(int v, int lane) {
#pragma unroll
    for (int off = 1; off < 64; off <<= 1) {
        int t = __shfl_up(v, off);
        if (lane >= off) v += t;
    }
    return v;
}

__global__ __launch_bounds__(256) void k_scan1(const int* __restrict__ cnt, int N,
                                               int* __restrict__ rowptr, int* __restrict__ blockSum,
                                               float* __restrict__ dinv) {
    __shared__ int wsum[4];
    int tid = threadIdx.x, lane = tid & 63, wid = tid >> 6;
    int base = blockIdx.x * 1024 + tid * 4;
    int c[4];
#pragma unroll
    for (int k = 0; k < 4; ++k) c[k] = (base + k < N) ? cnt[base + k] : 0;
#pragma unroll
    for (int k = 0; k < 4; ++k)
        if (base + k < N) dinv[base + k] = 1.0f / sqrtf((float)c[k] + 1.0f);  // +1 self-loop
    int t = c[0] + c[1] + c[2] + c[3];
    int incl = wave_incl_scan(t, lane);
    if (lane == 63) wsum[wid] = incl;
    __syncthreads();
    int woff = 0;
    for (int w = 0; w < wid; ++w) woff += wsum[w];
    int p = woff + incl - t;
#pragma unroll
    for (int k = 0; k < 4; ++k) {
        if (base + k < N) rowptr[base + k] = p;
        p += c[k];
    }
    if (tid == 255) blockSum[blockIdx.x] = woff + incl;
}

__global__ __launch_bounds__(256) void k_scan2(int* __restrict__ blockSum, int nb) {
    __shared__ int wsum[4];
    int tid = threadIdx.x, lane = tid & 63, wid = tid >> 6;
    int v = (tid < nb) ? blockSum[tid] : 0;
    int incl = wave_incl_scan(v, lane);
    if (lane == 63) wsum[wid] = incl;
    __syncthreads();
    int woff = 0;
    for (int w = 0; w < wid; ++w) woff += wsum[w];
    if (tid < nb) blockSum[tid] = woff + incl - v;
}

__global__ void k_scan3(int* __restrict__ rowptr, const int* __restrict__ blockSum, int N, int E) {
    int i = blockIdx.x * blockDim.x + threadIdx.x;
    if (i < N) rowptr[i] += blockSum[i >> 10];
    if (i == 0) rowptr[N] = E;
}

// ---------------- pos[e] = rowptr[dst[e]] + rank[e]  (in-place on rank) ----------------
__global__ void k_pos(const int* __restrict__ dst, const int* __restrict__ rowptr,
                      int* __restrict__ rank, int E) {
    int e = blockIdx.x * blockDim.x + threadIdx.x;
    if (e < E) rank[e] += rowptr[dst[e]];
}

// ---------------- CSR fill: atomic-free permutation store, swept by pos range ----------------
__global__ void k_fill(const int* __restrict__ src, const int* __restrict__ pos, int E,
                       int* __restrict__ csr_src, int lo, int hi) {
    int e = blockIdx.x * blockDim.x + threadIdx.x;
    if (e >= E) return;
    int c = pos[e];
    if (c < lo || c >= hi) return;
    csr_src[c] = src[e];
}

// ---------------- GEMM1: A = (x @ W1) * dinv ----------------
__global__ __launch_bounds__(256) void k_gemm1(
    const float* __restrict__ x, const float* __restrict__ W1,
    const float* __restrict__ dinv, int N, float* __restrict__ A) {
    __shared__ float sW[FIN * H];      // 32 KB
    __shared__ float sx[16][FIN];      // 8 KB
    int tid = threadIdx.x;
    for (int i = tid; i < FIN * H; i += 256) sW[i] = W1[i];
    int row0 = blockIdx.x * 16;
    for (int i = tid; i < 16 * (FIN / 4); i += 256) {
        int r = i / (FIN / 4), c = i % (FIN / 4);
        int row = row0 + r;
        float4 v = make_float4(0.f, 0.f, 0.f, 0.f);
        if (row < N) v = ((const float4*)(x + (size_t)row * FIN))[c];
        ((float4*)&sx[r][0])[c] = v;
    }
    __syncthreads();
    int col = tid & 63;
    int r0 = (tid >> 6) * 4;
    float acc[4] = {0.f, 0.f, 0.f, 0.f};
    for (int k = 0; k < FIN; ++k) {
        float w = sW[k * H + col];
#pragma unroll
        for (int r = 0; r < 4; ++r) acc[r] += sx[r0 + r][k] * w;
    }
#pragma unroll
    for (int r = 0; r < 4; ++r) {
        int row = row0 + r0 + r;
        if (row < N) A[(size_t)row * H + col] = acc[r] * dinv[row];
    }
}

// ---------------- GEMM2: g = relu(B + b1); A = (g @ W2) * dinv ----------------
__global__ __launch_bounds__(256) void k_gemm2(
    const float* __restrict__ B, const float* __restrict__ W2, const float* __restrict__ b1,
    const float* __restrict__ dinv, int N, float* __restrict__ A) {
    __shared__ float sW[H * H];        // 16 KB
    __shared__ float sh[16][H];        // 4 KB
    int tid = threadIdx.x;
    for (int i = tid; i < H * H; i += 256) sW[i] = W2[i];
    int row0 = blockIdx.x * 16;
    for (int i = tid; i < 16 * H; i += 256) {
        int r = i / H, c = i % H;
        int row = row0 + r;
        float v = 0.f;
        if (row < N) v = B[(size_t)row * H + c] + b1[c];
        sh[r][c] = fmaxf(v, 0.f);
    }
    __syncthreads();
    int col = tid & 63;
    int r0 = (tid >> 6) * 4;
    float acc[4] = {0.f, 0.f, 0.f, 0.f};
    for (int k = 0; k < H; ++k) {
        float w = sW[k * H + col];
#pragma unroll
        for (int r = 0; r < 4; ++r) acc[r] += sh[r0 + r][k] * w;
    }
#pragma unroll
    for (int r = 0; r < 4; ++r) {
        int row = row0 + r0 + r;
        if (row < N) A[(size_t)row * H + col] = acc[r] * dinv[row];
    }
}

// ---------------- gather: row = dinv[n] * (A[n] + sum_{s in in(n)} A[s]) ----------------
// FUSE=false: B[n] = row.   FUSE=true: g = relu(row + b2); out = [g.Wt+bt ; g.We+be]
__device__ inline void add4(float4& a, const float4& b) {
    a.x += b.x; a.y += b.y; a.z += b.z; a.w += b.w;
}

template<bool FUSE>
__global__ __launch_bounds__(256) void k_gather(
    const int* __restrict__ rowptr, const int* __restrict__ csr_src,
    const float* __restrict__ dinv, const float* __restrict__ A,
    float* __restrict__ B, int N,
    const float* __restrict__ b2, const float* __restrict__ Wt, const float* __restrict__ bt,
    const float* __restrict__ We, const float* __restrict__ be, float* __restrict__ out) {
    int node = blockIdx.x * 4 + (threadIdx.x >> 6);
    if (node >= N) return;
    int lane = threadIdx.x & 63;
    int grp = lane >> 4, sub = lane & 15;
    const float4* A4 = (const float4*)A;
    int beg = rowptr[node], end = rowptr[node + 1];
    float4 a0 = make_float4(0.f, 0.f, 0.f, 0.f), a1 = a0, a2 = a0, a3 = a0;
    if (grp == 0) a0 = A4[(size_t)node * 16 + sub];   // self-loop term
    for (int e0 = beg; e0 < end; e0 += 64) {
        int m = end - e0; if (m > 64) m = 64;
        int id = (lane < m) ? csr_src[e0 + lane] : 0;
        int c = 0;
        for (; c + 16 <= m; c += 16) {
            int s0 = __shfl(id, c + grp);
            int s1 = __shfl(id, c + 4 + grp);
            int s2 = __shfl(id, c + 8 + grp);
            int s3 = __shfl(id, c + 12 + grp);
            float4 v0 = A4[(size_t)s0 * 16 + sub];
            float4 v1 = A4[(size_t)s1 * 16 + sub];
            float4 v2 = A4[(size_t)s2 * 16 + sub];
            float4 v3 = A4[(size_t)s3 * 16 + sub];
            add4(a0, v0); add4(a1, v1); add4(a2, v2); add4(a3, v3);
        }
        for (; c < m; c += 4) {
            int cc = c + grp;
            int s = __shfl(id, cc < m ? cc : 0);
            if (cc < m) { float4 v = A4[(size_t)s * 16 + sub]; add4(a0, v); }
        }
    }
    add4(a0, a1); add4(a2, a3); add4(a0, a2);
    a0.x += __shfl_xor(a0.x, 16); a0.y += __shfl_xor(a0.y, 16);
    a0.z += __shfl_xor(a0.z, 16); a0.w += __shfl_xor(a0.w, 16);
    a0.x += __shfl_xor(a0.x, 32); a0.y += __shfl_xor(a0.y, 32);
    a0.z += __shfl_xor(a0.z, 32); a0.w += __shfl_xor(a0.w, 32);
    if (grp == 0) {
        float dv = dinv[node];
        a0.x *= dv; a0.y *= dv; a0.z *= dv; a0.w *= dv;
        if (!FUSE) {
            ((float4*)B)[(size_t)node * 16 + sub] = a0;
        } else {
            int f = sub * 4;
            float g0 = fmaxf(a0.x + b2[f + 0], 0.f);
            float g1 = fmaxf(a0.y + b2[f + 1], 0.f);
            float g2 = fmaxf(a0.z + b2[f + 2], 0.f);
            float g3 = fmaxf(a0.w + b2[f + 3], 0.f);
            float p1 = g0 * Wt[f] + g1 * Wt[f + 1] + g2 * Wt[f + 2] + g3 * Wt[f + 3];
            float p2 = g0 * We[f] + g1 * We[f + 1] + g2 * We[f + 2] + g3 * We[f + 3];
#pragma unroll
            for (int off = 1; off < 16; off <<= 1) {
                p1 += __shfl_xor(p1, off);
                p2 += __shfl_xor(p2, off);
            }
            if (sub == 0) {
                out[node] = p1 + bt[0];
                out[N + node] = p2 + be[0];
            }
        }
    }
}

extern "C" void kernel_launch(void* const* d_in, const int* in_sizes, int n_in,
                              void* d_out, int out_size, void* d_ws, size_t ws_size,
                              hipStream_t stream) {
    const float* x  = (const float*)d_in[0];
    const int* edge = (const int*)d_in[1];
    const float* W1 = (const float*)d_in[2];
    const float* b1 = (const float*)d_in[3];
    const float* W2 = (const float*)d_in[4];
    const float* b2 = (const float*)d_in[5];
    const float* Wt = (const float*)d_in[6];
    const float* bt = (const float*)d_in[7];
    const float* We = (const float*)d_in[8];
    const float* be = (const float*)d_in[9];

    int N = in_sizes[0] / FIN;
    int E = in_sizes[1] / 2;
    const int* src = edge;
    const int* dst = edge + E;

    char* ws = (char*)d_ws;
    size_t off = 0;
    auto alloc = [&](size_t bytes) {
        void* p = ws + off;
        off += (bytes + 255) & ~size_t(255);
        return p;
    };
    int*   cnt      = (int*)alloc((size_t)N * sizeof(int));
    float* dinv     = (float*)alloc((size_t)N * sizeof(float));
    int*   rowptr   = (int*)alloc((size_t)(N + 1) * sizeof(int));
    int*   blockSum = (int*)alloc(256 * sizeof(int));
    int*   rank     = (int*)alloc((size_t)E * sizeof(int));   // becomes pos[]
    int*   csr_src  = (int*)alloc((size_t)E * sizeof(int));
    float* A        = (float*)alloc((size_t)N * H * sizeof(float));
    float* B        = (float*)alloc((size_t)N * H * sizeof(float));

    int nb = (N + 1023) / 1024;
    int egrid = (E + 255) / 256;

    hipMemsetAsync(cnt, 0, (size_t)N * sizeof(int), stream);
    k_deg_rank<<<egrid, 256, 0, stream>>>(dst, E, cnt, rank);

    // CSR build (by dst): scan -> pos -> atomic-free swept permutation store
    k_scan1<<<nb, 256, 0, stream>>>(cnt, N, rowptr, blockSum, dinv);
    k_scan2<<<1, 256, 0, stream>>>(blockSum, nb);
    k_scan3<<<(N + 255) / 256, 256, 0, stream>>>(rowptr, blockSum, N, E);
    k_pos<<<egrid, 256, 0, stream>>>(dst, rowptr, rank, E);
    for (int s = 0; s < NSWEEP; ++s) {
        int lo = (int)((long long)E * s / NSWEEP);
        int hi = (int)((long long)E * (s + 1) / NSWEEP);
        k_fill<<<egrid, 256, 0, stream>>>(src, rank, E, csr_src, lo, hi);
    }

    // layer 1
    k_gemm1<<<(N + 15) / 16, 256, 0, stream>>>(x, W1, dinv, N, A);
    k_gather<false><<<(N + 3) / 4, 256, 0, stream>>>(rowptr, csr_src, dinv, A, B, N,
                                                     nullptr, nullptr, nullptr, nullptr, nullptr, nullptr);

    // layer 2 + fused heads
    k_gemm2<<<(N + 15) / 16, 256, 0, stream>>>(B, W2, b1, dinv, N, A);
    k_gather<true><<<(N + 3) / 4, 256, 0, stream>>>(rowptr, csr_src, dinv, A, nullptr, N,
                                                    b2, Wt, bt, We, be, (float*)d_out);
}

// Round 5
// 433.765 us; speedup vs baseline: 13.1250x; 1.3028x over previous
//
#include <hip/hip_runtime.h>
#include <math.h>

constexpr int H = 64;
constexpr int FIN = 128;
constexpr int BIN_SHIFT = 7;          // 128 nodes per bin
constexpr int BIN_NODES = 1 << BIN_SHIFT;
constexpr int MAX_BINS = 1024;        // supports N <= 131072
constexpr int BIN_CAP = 5120;         // mean 4096 + 16 sigma
constexpr int SRC_BITS = 25;          // word = dstLow7 << 25 | src  (N < 2^25)
constexpr unsigned SRC_MASK = (1u << SRC_BITS) - 1;

__device__ inline int wave_incl_scan(int v, int lane) {
#pragma unroll
    for (int off = 1; off < 64; off <<= 1) {
        int t = __shfl_up(v, off);
        if (lane >= off) v += t;
    }
    return v;
}

// ---------------- cursor init: cursor[b] = b * BIN_CAP ----------------
__global__ void k_initcur(int* __restrict__ cursor, int nbins) {
    int i = blockIdx.x * blockDim.x + threadIdx.x;
    if (i < nbins) cursor[i] = i * BIN_CAP;
}

// ---------------- bin scatter: LDS hist -> run reservation -> packed scatter ----------------
__global__ __launch_bounds__(256) void k_bin(
    const int* __restrict__ src, const int* __restrict__ dst, int E, int nbins,
    int* __restrict__ cursor, int* __restrict__ binned) {
    __shared__ int hist[MAX_BINS];
    __shared__ int base[MAX_BINS];
    int tid = threadIdx.x;
    long long e0 = (long long)E * blockIdx.x / gridDim.x;
    long long e1 = (long long)E * (blockIdx.x + 1) / gridDim.x;
    for (int i = tid; i < nbins; i += 256) hist[i] = 0;
    __syncthreads();
    for (long long e = e0 + tid; e < e1; e += 256)
        atomicAdd(&hist[dst[e] >> BIN_SHIFT], 1);
    __syncthreads();
    for (int i = tid; i < nbins; i += 256) {
        int h = hist[i];
        base[i] = h ? atomicAdd(&cursor[i], h) : 0;
        hist[i] = 0;
    }
    __syncthreads();
    for (long long e = e0 + tid; e < e1; e += 256) {
        int d = dst[e];
        int b = d >> BIN_SHIFT;
        int r = atomicAdd(&hist[b], 1);   // re-rank: distinct within (block,bin) is all we need
        binned[base[b] + r] = (int)(((unsigned)(d & (BIN_NODES - 1)) << SRC_BITS) | (unsigned)src[e]);
    }
}

// ---------------- bin scan: binbase = exclscan(cursor[b] - b*CAP) ----------------
__global__ __launch_bounds__(256) void k_binscan(
    const int* __restrict__ cursor, int nbins,
    int* __restrict__ binbase, int* __restrict__ rowptr, int N, int E) {
    __shared__ int wsum[4];
    int tid = threadIdx.x, lane = tid & 63, wid = tid >> 6;
    int b0 = tid * 4;
    int c[4];
#pragma unroll
    for (int k = 0; k < 4; ++k) {
        int b = b0 + k;
        c[k] = (b < nbins) ? cursor[b] - b * BIN_CAP : 0;
    }
    int t = c[0] + c[1] + c[2] + c[3];
    int incl = wave_incl_scan(t, lane);
    if (lane == 63) wsum[wid] = incl;
    __syncthreads();
    int woff = 0;
    for (int w = 0; w < wid; ++w) woff += wsum[w];
    int p = woff + incl - t;
#pragma unroll
    for (int k = 0; k < 4; ++k) {
        int b = b0 + k;
        if (b < nbins) binbase[b] = p;
        p += c[k];
    }
    if (tid == 0) rowptr[N] = E;
}

// ---------------- per-bin sort: csr_src + rowptr + dinv, all LDS-local ----------------
__global__ __launch_bounds__(256) void k_binsort(
    const int* __restrict__ cursor, const int* __restrict__ binbase,
    const int* __restrict__ binned, int N,
    int* __restrict__ csr_src, int* __restrict__ rowptr, float* __restrict__ dinv) {
    __shared__ int cnt[BIN_NODES];
    __shared__ int excl[BIN_NODES];
    __shared__ int rnk[BIN_NODES];
    __shared__ int wsum[2];
    int bin = blockIdx.x;
    int tid = threadIdx.x, lane = tid & 63, wid = tid >> 6;
    int n = cursor[bin] - bin * BIN_CAP;
    int gbase = binbase[bin];
    const int* bp = binned + (size_t)bin * BIN_CAP;
    if (tid < BIN_NODES) { cnt[tid] = 0; rnk[tid] = 0; }
    __syncthreads();
    for (int i = tid; i < n; i += 256)
        atomicAdd(&cnt[((unsigned)bp[i]) >> SRC_BITS], 1);
    __syncthreads();
    int v = (tid < BIN_NODES) ? cnt[tid] : 0;
    int incl = wave_incl_scan(v, lane);
    if (tid < BIN_NODES && lane == 63) wsum[wid] = incl;
    __syncthreads();
    if (tid < BIN_NODES) {
        int off = (wid == 1) ? wsum[0] : 0;
        int ex = off + incl - v;
        excl[tid] = ex;
        int node = bin * BIN_NODES + tid;
        if (node < N) {
            rowptr[node] = gbase + ex;
            dinv[node] = 1.0f / sqrtf((float)v + 1.0f);  // +1 self-loop
        }
    }
    __syncthreads();
    for (int i = tid; i < n; i += 256) {
        unsigned w = (unsigned)bp[i];
        int dl = w >> SRC_BITS;
        int r = atomicAdd(&rnk[dl], 1);
        csr_src[gbase + excl[dl] + r] = (int)(w & SRC_MASK);
    }
}

// ---------------- GEMM1: A = (x @ W1) * dinv ----------------
__global__ __launch_bounds__(256) void k_gemm1(
    const float* __restrict__ x, const float* __restrict__ W1,
    const float* __restrict__ dinv, int N, float* __restrict__ A) {
    __shared__ float sW[FIN * H];      // 32 KB
    __shared__ float sx[16][FIN];      // 8 KB
    int tid = threadIdx.x;
    for (int i = tid; i < FIN * H; i += 256) sW[i] = W1[i];
    int row0 = blockIdx.x * 16;
    for (int i = tid; i < 16 * (FIN / 4); i += 256) {
        int r = i / (FIN / 4), c = i % (FIN / 4);
        int row = row0 + r;
        float4 v = make_float4(0.f, 0.f, 0.f, 0.f);
        if (row < N) v = ((const float4*)(x + (size_t)row * FIN))[c];
        ((float4*)&sx[r][0])[c] = v;
    }
    __syncthreads();
    int col = tid & 63;
    int r0 = (tid >> 6) * 4;
    float acc[4] = {0.f, 0.f, 0.f, 0.f};
    for (int k = 0; k < FIN; ++k) {
        float w = sW[k * H + col];
#pragma unroll
        for (int r = 0; r < 4; ++r) acc[r] += sx[r0 + r][k] * w;
    }
#pragma unroll
    for (int r = 0; r < 4; ++r) {
        int row = row0 + r0 + r;
        if (row < N) A[(size_t)row * H + col] = acc[r] * dinv[row];
    }
}

// ---------------- GEMM2: g = relu(B + b1); A = (g @ W2) * dinv ----------------
__global__ __launch_bounds__(256) void k_gemm2(
    const float* __restrict__ B, const float* __restrict__ W2, const float* __restrict__ b1,
    const float* __restrict__ dinv, int N, float* __restrict__ A) {
    __shared__ float sW[H * H];        // 16 KB
    __shared__ float sh[16][H];        // 4 KB
    int tid = threadIdx.x;
    for (int i = tid; i < H * H; i += 256) sW[i] = W2[i];
    int row0 = blockIdx.x * 16;
    for (int i = tid; i < 16 * H; i += 256) {
        int r = i / H, c = i % H;
        int row = row0 + r;
        float v = 0.f;
        if (row < N) v = B[(size_t)row * H + c] + b1[c];
        sh[r][c] = fmaxf(v, 0.f);
    }
    __syncthreads();
    int col = tid & 63;
    int r0 = (tid >> 6) * 4;
    float acc[4] = {0.f, 0.f, 0.f, 0.f};
    for (int k = 0; k < H; ++k) {
        float w = sW[k * H + col];
#pragma unroll
        for (int r = 0; r < 4; ++r) acc[r] += sh[r0 + r][k] * w;
    }
#pragma unroll
    for (int r = 0; r < 4; ++r) {
        int row = row0 + r0 + r;
        if (row < N) A[(size_t)row * H + col] = acc[r] * dinv[row];
    }
}

// ---------------- gather: row = dinv[n] * (A[n] + sum_{s in in(n)} A[s]) ----------------
__device__ inline void add4(float4& a, const float4& b) {
    a.x += b.x; a.y += b.y; a.z += b.z; a.w += b.w;
}

template<bool FUSE>
__global__ __launch_bounds__(256) void k_gather(
    const int* __restrict__ rowptr, const int* __restrict__ csr_src,
    const float* __restrict__ dinv, const float* __restrict__ A,
    float* __restrict__ B, int N,
    const float* __restrict__ b2, const float* __restrict__ Wt, const float* __restrict__ bt,
    const float* __restrict__ We, const float* __restrict__ be, float* __restrict__ out) {
    int node = blockIdx.x * 4 + (threadIdx.x >> 6);
    if (node >= N) return;
    int lane = threadIdx.x & 63;
    int grp = lane >> 4, sub = lane & 15;
    const float4* A4 = (const float4*)A;
    int beg = rowptr[node], end = rowptr[node + 1];
    float4 a0 = make_float4(0.f, 0.f, 0.f, 0.f), a1 = a0, a2 = a0, a3 = a0;
    if (grp == 0) a0 = A4[(size_t)node * 16 + sub];   // self-loop term
    for (int e0 = beg; e0 < end; e0 += 64) {
        int m = end - e0; if (m > 64) m = 64;
        int id = (lane < m) ? csr_src[e0 + lane] : 0;
        int c = 0;
        for (; c + 16 <= m; c += 16) {
            int s0 = __shfl(id, c + grp);
            int s1 = __shfl(id, c + 4 + grp);
            int s2 = __shfl(id, c + 8 + grp);
            int s3 = __shfl(id, c + 12 + grp);
            float4 v0 = A4[(size_t)s0 * 16 + sub];
            float4 v1 = A4[(size_t)s1 * 16 + sub];
            float4 v2 = A4[(size_t)s2 * 16 + sub];
            float4 v3 = A4[(size_t)s3 * 16 + sub];
            add4(a0, v0); add4(a1, v1); add4(a2, v2); add4(a3, v3);
        }
        for (; c < m; c += 4) {
            int cc = c + grp;
            int s = __shfl(id, cc < m ? cc : 0);
            if (cc < m) { float4 v = A4[(size_t)s * 16 + sub]; add4(a0, v); }
        }
    }
    add4(a0, a1); add4(a2, a3); add4(a0, a2);
    a0.x += __shfl_xor(a0.x, 16); a0.y += __shfl_xor(a0.y, 16);
    a0.z += __shfl_xor(a0.z, 16); a0.w += __shfl_xor(a0.w, 16);
    a0.x += __shfl_xor(a0.x, 32); a0.y += __shfl_xor(a0.y, 32);
    a0.z += __shfl_xor(a0.z, 32); a0.w += __shfl_xor(a0.w, 32);
    if (grp == 0) {
        float dv = dinv[node];
        a0.x *= dv; a0.y *= dv; a0.z *= dv; a0.w *= dv;
        if (!FUSE) {
            ((float4*)B)[(size_t)node * 16 + sub] = a0;
        } else {
            int f = sub * 4;
            float g0 = fmaxf(a0.x + b2[f + 0], 0.f);
            float g1 = fmaxf(a0.y + b2[f + 1], 0.f);
            float g2 = fmaxf(a0.z + b2[f + 2], 0.f);
            float g3 = fmaxf(a0.w + b2[f + 3], 0.f);
            float p1 = g0 * Wt[f] + g1 * Wt[f + 1] + g2 * Wt[f + 2] + g3 * Wt[f + 3];
            float p2 = g0 * We[f] + g1 * We[f + 1] + g2 * We[f + 2] + g3 * We[f + 3];
#pragma unroll
            for (int off = 1; off < 16; off <<= 1) {
                p1 += __shfl_xor(p1, off);
                p2 += __shfl_xor(p2, off);
            }
            if (sub == 0) {
                out[node] = p1 + bt[0];
                out[N + node] = p2 + be[0];
            }
        }
    }
}

extern "C" void kernel_launch(void* const* d_in, const int* in_sizes, int n_in,
                              void* d_out, int out_size, void* d_ws, size_t ws_size,
                              hipStream_t stream) {
    const float* x  = (const float*)d_in[0];
    const int* edge = (const int*)d_in[1];
    const float* W1 = (const float*)d_in[2];
    const float* b1 = (const float*)d_in[3];
    const float* W2 = (const float*)d_in[4];
    const float* b2 = (const float*)d_in[5];
    const float* Wt = (const float*)d_in[6];
    const float* bt = (const float*)d_in[7];
    const float* We = (const float*)d_in[8];
    const float* be = (const float*)d_in[9];

    int N = in_sizes[0] / FIN;
    int E = in_sizes[1] / 2;
    const int* src = edge;
    const int* dst = edge + E;
    int nbins = (N + BIN_NODES - 1) >> BIN_SHIFT;

    char* ws = (char*)d_ws;
    size_t off = 0;
    auto alloc = [&](size_t bytes) {
        void* p = ws + off;
        off += (bytes + 255) & ~size_t(255);
        return p;
    };
    float* dinv    = (float*)alloc((size_t)N * sizeof(float));
    int*   rowptr  = (int*)alloc((size_t)(N + 1) * sizeof(int));
    int*   cursor  = (int*)alloc((size_t)nbins * sizeof(int));
    int*   binbase = (int*)alloc((size_t)nbins * sizeof(int));
    int*   binned  = (int*)alloc((size_t)nbins * BIN_CAP * sizeof(int));
    int*   csr_src = (int*)alloc((size_t)E * sizeof(int));
    float* A       = (float*)alloc((size_t)N * H * sizeof(float));
    float* B       = (float*)alloc((size_t)N * H * sizeof(float));

    // CSR build via two-level bin sort (no per-edge global atomics)
    k_initcur<<<(nbins + 255) / 256, 256, 0, stream>>>(cursor, nbins);
    k_bin<<<512, 256, 0, stream>>>(src, dst, E, nbins, cursor, binned);
    k_binscan<<<1, 256, 0, stream>>>(cursor, nbins, binbase, rowptr, N, E);
    k_binsort<<<nbins, 256, 0, stream>>>(cursor, binbase, binned, N, csr_src, rowptr, dinv);

    // layer 1
    k_gemm1<<<(N + 15) / 16, 256, 0, stream>>>(x, W1, dinv, N, A);
    k_gather<false><<<(N + 3) / 4, 256, 0, stream>>>(rowptr, csr_src, dinv, A, B, N,
                                                     nullptr, nullptr, nullptr, nullptr, nullptr, nullptr);

    // layer 2 + fused heads
    k_gemm2<<<(N + 15) / 16, 256, 0, stream>>>(B, W2, b1, dinv, N, A);
    k_gather<true><<<(N + 3) / 4, 256, 0, stream>>>(rowptr, csr_src, dinv, A, nullptr, N,
                                                    b2, Wt, bt, We, be, (float*)d_out);
}

// Round 6
// 342.643 us; speedup vs baseline: 16.6154x; 1.2659x over previous
//
#include <hip/hip_runtime.h>
#include <math.h>

constexpr int H = 64;
constexpr int FIN = 128;
constexpr int BIN_SHIFT = 7;          // 128 nodes per bin
constexpr int BIN_NODES = 1 << BIN_SHIFT;
constexpr int MAX_BINS = 1024;        // supports N <= 131072
constexpr int BIN_CAP = 5120;         // mean 4096 + 16 sigma
constexpr int SRC_BITS = 25;          // word = dstLow7 << 25 | src  (N < 2^25)
constexpr unsigned SRC_MASK = (1u << SRC_BITS) - 1;

__device__ inline float bf2f(unsigned short u) {
    unsigned v = ((unsigned)u) << 16;
    return __builtin_bit_cast(float, v);
}
__device__ inline unsigned short f2bf(float f) {
    unsigned u = __builtin_bit_cast(unsigned, f);
    unsigned rnd = 0x7FFFu + ((u >> 16) & 1u);   // RTN-even
    return (unsigned short)((u + rnd) >> 16);
}

__device__ inline int wave_incl_scan(int v, int lane) {
#pragma unroll
    for (int off = 1; off < 64; off <<= 1) {
        int t = __shfl_up(v, off);
        if (lane >= off) v += t;
    }
    return v;
}

// ---------------- cursor init: cursor[b] = b * BIN_CAP ----------------
__global__ void k_initcur(int* __restrict__ cursor, int nbins) {
    int i = blockIdx.x * blockDim.x + threadIdx.x;
    if (i < nbins) cursor[i] = i * BIN_CAP;
}

// ---------------- bin scatter: LDS hist -> run reservation -> packed scatter ----------------
__global__ __launch_bounds__(256) void k_bin(
    const int* __restrict__ src, const int* __restrict__ dst, int E, int nbins,
    int* __restrict__ cursor, int* __restrict__ binned) {
    __shared__ int hist[MAX_BINS];
    __shared__ int base[MAX_BINS];
    int tid = threadIdx.x;
    long long e0 = (long long)E * blockIdx.x / gridDim.x;
    long long e1 = (long long)E * (blockIdx.x + 1) / gridDim.x;
    for (int i = tid; i < nbins; i += 256) hist[i] = 0;
    __syncthreads();
    for (long long e = e0 + tid; e < e1; e += 256)
        atomicAdd(&hist[dst[e] >> BIN_SHIFT], 1);
    __syncthreads();
    for (int i = tid; i < nbins; i += 256) {
        int h = hist[i];
        base[i] = h ? atomicAdd(&cursor[i], h) : 0;
        hist[i] = 0;
    }
    __syncthreads();
    for (long long e = e0 + tid; e < e1; e += 256) {
        int d = dst[e];
        int b = d >> BIN_SHIFT;
        int r = atomicAdd(&hist[b], 1);   // re-rank: distinct within (block,bin) is all we need
        binned[base[b] + r] = (int)(((unsigned)(d & (BIN_NODES - 1)) << SRC_BITS) | (unsigned)src[e]);
    }
}

// ---------------- bin scan: binbase = exclscan(cursor[b] - b*CAP) ----------------
__global__ __launch_bounds__(256) void k_binscan(
    const int* __restrict__ cursor, int nbins,
    int* __restrict__ binbase, int* __restrict__ rowptr, int N, int E) {
    __shared__ int wsum[4];
    int tid = threadIdx.x, lane = tid & 63, wid = tid >> 6;
    int b0 = tid * 4;
    int c[4];
#pragma unroll
    for (int k = 0; k < 4; ++k) {
        int b = b0 + k;
        c[k] = (b < nbins) ? cursor[b] - b * BIN_CAP : 0;
    }
    int t = c[0] + c[1] + c[2] + c[3];
    int incl = wave_incl_scan(t, lane);
    if (lane == 63) wsum[wid] = incl;
    __syncthreads();
    int woff = 0;
    for (int w = 0; w < wid; ++w) woff += wsum[w];
    int p = woff + incl - t;
#pragma unroll
    for (int k = 0; k < 4; ++k) {
        int b = b0 + k;
        if (b < nbins) binbase[b] = p;
        p += c[k];
    }
    if (tid == 0) rowptr[N] = E;
}

// ---------------- per-bin sort: csr_src + rowptr + dinv, all LDS-local ----------------
__global__ __launch_bounds__(256) void k_binsort(
    const int* __restrict__ cursor, const int* __restrict__ binbase,
    const int* __restrict__ binned, int N,
    int* __restrict__ csr_src, int* __restrict__ rowptr, float* __restrict__ dinv) {
    __shared__ int cnt[BIN_NODES];
    __shared__ int excl[BIN_NODES];
    __shared__ int rnk[BIN_NODES];
    __shared__ int wsum[2];
    int bin = blockIdx.x;
    int tid = threadIdx.x, lane = tid & 63, wid = tid >> 6;
    int n = cursor[bin] - bin * BIN_CAP;
    int gbase = binbase[bin];
    const int* bp = binned + (size_t)bin * BIN_CAP;
    if (tid < BIN_NODES) { cnt[tid] = 0; rnk[tid] = 0; }
    __syncthreads();
    for (int i = tid; i < n; i += 256)
        atomicAdd(&cnt[((unsigned)bp[i]) >> SRC_BITS], 1);
    __syncthreads();
    int v = (tid < BIN_NODES) ? cnt[tid] : 0;
    int incl = wave_incl_scan(v, lane);
    if (tid < BIN_NODES && lane == 63) wsum[wid] = incl;
    __syncthreads();
    if (tid < BIN_NODES) {
        int off = (wid == 1) ? wsum[0] : 0;
        int ex = off + incl - v;
        excl[tid] = ex;
        int node = bin * BIN_NODES + tid;
        if (node < N) {
            rowptr[node] = gbase + ex;
            dinv[node] = 1.0f / sqrtf((float)v + 1.0f);  // +1 self-loop
        }
    }
    __syncthreads();
    for (int i = tid; i < n; i += 256) {
        unsigned w = (unsigned)bp[i];
        int dl = w >> SRC_BITS;
        int r = atomicAdd(&rnk[dl], 1);
        csr_src[gbase + excl[dl] + r] = (int)(w & SRC_MASK);
    }
}

// ---------------- GEMM1: A16 = bf16((x @ W1) * dinv) ----------------
__global__ __launch_bounds__(256) void k_gemm1(
    const float* __restrict__ x, const float* __restrict__ W1,
    const float* __restrict__ dinv, int N, unsigned short* __restrict__ A16) {
    __shared__ float sW[FIN * H];      // 32 KB
    __shared__ float sx[16][FIN];      // 8 KB
    int tid = threadIdx.x;
    for (int i = tid; i < FIN * H; i += 256) sW[i] = W1[i];
    int row0 = blockIdx.x * 16;
    for (int i = tid; i < 16 * (FIN / 4); i += 256) {
        int r = i / (FIN / 4), c = i % (FIN / 4);
        int row = row0 + r;
        float4 v = make_float4(0.f, 0.f, 0.f, 0.f);
        if (row < N) v = ((const float4*)(x + (size_t)row * FIN))[c];
        ((float4*)&sx[r][0])[c] = v;
    }
    __syncthreads();
    int col = tid & 63;
    int r0 = (tid >> 6) * 4;
    float acc[4] = {0.f, 0.f, 0.f, 0.f};
    for (int k = 0; k < FIN; ++k) {
        float w = sW[k * H + col];
#pragma unroll
        for (int r = 0; r < 4; ++r) acc[r] += sx[r0 + r][k] * w;
    }
#pragma unroll
    for (int r = 0; r < 4; ++r) {
        int row = row0 + r0 + r;
        if (row < N) A16[(size_t)row * H + col] = f2bf(acc[r] * dinv[row]);
    }
}

// ---------------- GEMM2: g = relu(B + b1); A16 = bf16((g @ W2) * dinv) ----------------
__global__ __launch_bounds__(256) void k_gemm2(
    const float* __restrict__ B, const float* __restrict__ W2, const float* __restrict__ b1,
    const float* __restrict__ dinv, int N, unsigned short* __restrict__ A16) {
    __shared__ float sW[H * H];        // 16 KB
    __shared__ float sh[16][H];        // 4 KB
    int tid = threadIdx.x;
    for (int i = tid; i < H * H; i += 256) sW[i] = W2[i];
    int row0 = blockIdx.x * 16;
    for (int i = tid; i < 16 * H; i += 256) {
        int r = i / H, c = i % H;
        int row = row0 + r;
        float v = 0.f;
        if (row < N) v = B[(size_t)row * H + c] + b1[c];
        sh[r][c] = fmaxf(v, 0.f);
    }
    __syncthreads();
    int col = tid & 63;
    int r0 = (tid >> 6) * 4;
    float acc[4] = {0.f, 0.f, 0.f, 0.f};
    for (int k = 0; k < H; ++k) {
        float w = sW[k * H + col];
#pragma unroll
        for (int r = 0; r < 4; ++r) acc[r] += sh[r0 + r][k] * w;
    }
#pragma unroll
    for (int r = 0; r < 4; ++r) {
        int row = row0 + r0 + r;
        if (row < N) A16[(size_t)row * H + col] = f2bf(acc[r] * dinv[row]);
    }
}

// ---------------- gather: row = dinv[n] * (A[n] + sum_{s in in(n)} A[s]),  A in bf16 ----------------
__device__ inline void addbf4(float4& a, ushort4 u) {
    a.x += bf2f(u.x); a.y += bf2f(u.y); a.z += bf2f(u.z); a.w += bf2f(u.w);
}
__device__ inline void add4(float4& a, const float4& b) {
    a.x += b.x; a.y += b.y; a.z += b.z; a.w += b.w;
}

template<bool FUSE>
__global__ __launch_bounds__(256) void k_gather(
    const int* __restrict__ rowptr, const int* __restrict__ csr_src,
    const float* __restrict__ dinv, const unsigned short* __restrict__ A16,
    float* __restrict__ B, int N,
    const float* __restrict__ b2, const float* __restrict__ Wt, const float* __restrict__ bt,
    const float* __restrict__ We, const float* __restrict__ be, float* __restrict__ out) {
    int node = blockIdx.x * 4 + (threadIdx.x >> 6);
    if (node >= N) return;
    int lane = threadIdx.x & 63;
    int grp = lane >> 4, sub = lane & 15;
    const ushort4* A4 = (const ushort4*)A16;     // row = 16 x ushort4
    int beg = rowptr[node], end = rowptr[node + 1];
    float4 a0 = make_float4(0.f, 0.f, 0.f, 0.f), a1 = a0, a2 = a0, a3 = a0;
    if (grp == 0) addbf4(a0, A4[(size_t)node * 16 + sub]);   // self-loop term
    for (int e0 = beg; e0 < end; e0 += 64) {
        int m = end - e0; if (m > 64) m = 64;
        int id = (lane < m) ? csr_src[e0 + lane] : 0;
        int c = 0;
        for (; c + 16 <= m; c += 16) {
            int s0 = __shfl(id, c + grp);
            int s1 = __shfl(id, c + 4 + grp);
            int s2 = __shfl(id, c + 8 + grp);
            int s3 = __shfl(id, c + 12 + grp);
            ushort4 v0 = A4[(size_t)s0 * 16 + sub];
            ushort4 v1 = A4[(size_t)s1 * 16 + sub];
            ushort4 v2 = A4[(size_t)s2 * 16 + sub];
            ushort4 v3 = A4[(size_t)s3 * 16 + sub];
            addbf4(a0, v0); addbf4(a1, v1); addbf4(a2, v2); addbf4(a3, v3);
        }
        for (; c < m; c += 4) {
            int cc = c + grp;
            int s = __shfl(id, cc < m ? cc : 0);
            if (cc < m) addbf4(a0, A4[(size_t)s * 16 + sub]);
        }
    }
    add4(a0, a1); add4(a2, a3); add4(a0, a2);
    a0.x += __shfl_xor(a0.x, 16); a0.y += __shfl_xor(a0.y, 16);
    a0.z += __shfl_xor(a0.z, 16); a0.w += __shfl_xor(a0.w, 16);
    a0.x += __shfl_xor(a0.x, 32); a0.y += __shfl_xor(a0.y, 32);
    a0.z += __shfl_xor(a0.z, 32); a0.w += __shfl_xor(a0.w, 32);
    if (grp == 0) {
        float dv = dinv[node];
        a0.x *= dv; a0.y *= dv; a0.z *= dv; a0.w *= dv;
        if (!FUSE) {
            ((float4*)B)[(size_t)node * 16 + sub] = a0;
        } else {
            int f = sub * 4;
            float g0 = fmaxf(a0.x + b2[f + 0], 0.f);
            float g1 = fmaxf(a0.y + b2[f + 1], 0.f);
            float g2 = fmaxf(a0.z + b2[f + 2], 0.f);
            float g3 = fmaxf(a0.w + b2[f + 3], 0.f);
            float p1 = g0 * Wt[f] + g1 * Wt[f + 1] + g2 * Wt[f + 2] + g3 * Wt[f + 3];
            float p2 = g0 * We[f] + g1 * We[f + 1] + g2 * We[f + 2] + g3 * We[f + 3];
#pragma unroll
            for (int off = 1; off < 16; off <<= 1) {
                p1 += __shfl_xor(p1, off);
                p2 += __shfl_xor(p2, off);
            }
            if (sub == 0) {
                out[node] = p1 + bt[0];
                out[N + node] = p2 + be[0];
            }
        }
    }
}

extern "C" void kernel_launch(void* const* d_in, const int* in_sizes, int n_in,
                              void* d_out, int out_size, void* d_ws, size_t ws_size,
                              hipStream_t stream) {
    const float* x  = (const float*)d_in[0];
    const int* edge = (const int*)d_in[1];
    const float* W1 = (const float*)d_in[2];
    const float* b1 = (const float*)d_in[3];
    const float* W2 = (const float*)d_in[4];
    const float* b2 = (const float*)d_in[5];
    const float* Wt = (const float*)d_in[6];
    const float* bt = (const float*)d_in[7];
    const float* We = (const float*)d_in[8];
    const float* be = (const float*)d_in[9];

    int N = in_sizes[0] / FIN;
    int E = in_sizes[1] / 2;
    const int* src = edge;
    const int* dst = edge + E;
    int nbins = (N + BIN_NODES - 1) >> BIN_SHIFT;

    char* ws = (char*)d_ws;
    size_t off = 0;
    auto alloc = [&](size_t bytes) {
        void* p = ws + off;
        off += (bytes + 255) & ~size_t(255);
        return p;
    };
    float* dinv    = (float*)alloc((size_t)N * sizeof(float));
    int*   rowptr  = (int*)alloc((size_t)(N + 1) * sizeof(int));
    int*   cursor  = (int*)alloc((size_t)nbins * sizeof(int));
    int*   binbase = (int*)alloc((size_t)nbins * sizeof(int));
    int*   binned  = (int*)alloc((size_t)nbins * BIN_CAP * sizeof(int));
    int*   csr_src = (int*)alloc((size_t)E * sizeof(int));
    unsigned short* A16 = (unsigned short*)alloc((size_t)N * H * sizeof(unsigned short));
    float* B       = (float*)alloc((size_t)N * H * sizeof(float));

    // CSR build via two-level bin sort (no per-edge global atomics)
    k_initcur<<<(nbins + 255) / 256, 256, 0, stream>>>(cursor, nbins);
    k_bin<<<512, 256, 0, stream>>>(src, dst, E, nbins, cursor, binned);
    k_binscan<<<1, 256, 0, stream>>>(cursor, nbins, binbase, rowptr, N, E);
    k_binsort<<<nbins, 256, 0, stream>>>(cursor, binbase, binned, N, csr_src, rowptr, dinv);

    // layer 1
    k_gemm1<<<(N + 15) / 16, 256, 0, stream>>>(x, W1, dinv, N, A16);
    k_gather<false><<<(N + 3) / 4, 256, 0, stream>>>(rowptr, csr_src, dinv, A16, B, N,
                                                     nullptr, nullptr, nullptr, nullptr, nullptr, nullptr);

    // layer 2 + fused heads
    k_gemm2<<<(N + 15) / 16, 256, 0, stream>>>(B, W2, b1, dinv, N, A16);
    k_gather<true><<<(N + 3) / 4, 256, 0, stream>>>(rowptr, csr_src, dinv, A16, nullptr, N,
                                                    b2, Wt, bt, We, be, (float*)d_out);
}

// Round 7
// 311.350 us; speedup vs baseline: 18.2854x; 1.1005x over previous
//
#include <hip/hip_runtime.h>
#include <math.h>

constexpr int H = 64;
constexpr int FIN = 128;
constexpr int BIN_SHIFT = 7;          // 128 nodes per bin
constexpr int BIN_NODES = 1 << BIN_SHIFT;
constexpr int MAX_BINS = 1024;        // supports N <= 131072
constexpr int BIN_CAP = 5120;         // mean 4096 + 16 sigma
constexpr int SRC_BITS = 25;          // word = dstLow7 << 25 | src  (N < 2^25)
constexpr unsigned SRC_MASK = (1u << SRC_BITS) - 1;

__device__ inline float bf2f(unsigned short u) {
    unsigned v = ((unsigned)u) << 16;
    return __builtin_bit_cast(float, v);
}
__device__ inline unsigned short f2bf(float f) {
    unsigned u = __builtin_bit_cast(unsigned, f);
    unsigned rnd = 0x7FFFu + ((u >> 16) & 1u);   // RTN-even
    return (unsigned short)((u + rnd) >> 16);
}

__device__ inline int wave_incl_scan(int v, int lane) {
#pragma unroll
    for (int off = 1; off < 64; off <<= 1) {
        int t = __shfl_up(v, off);
        if (lane >= off) v += t;
    }
    return v;
}

// ---------------- cursor init: cursor[b] = b * BIN_CAP ----------------
__global__ void k_initcur(int* __restrict__ cursor, int nbins) {
    int i = blockIdx.x * blockDim.x + threadIdx.x;
    if (i < nbins) cursor[i] = i * BIN_CAP;
}

// ---------------- bin scatter: LDS hist -> run reservation -> packed scatter ----------------
__global__ __launch_bounds__(256) void k_bin(
    const int* __restrict__ src, const int* __restrict__ dst, int E, int nbins,
    int* __restrict__ cursor, int* __restrict__ binned) {
    __shared__ int hist[MAX_BINS];
    __shared__ int base[MAX_BINS];
    int tid = threadIdx.x;
    long long e0 = (long long)E * blockIdx.x / gridDim.x;
    long long e1 = (long long)E * (blockIdx.x + 1) / gridDim.x;
    for (int i = tid; i < nbins; i += 256) hist[i] = 0;
    __syncthreads();
    for (long long e = e0 + tid; e < e1; e += 256)
        atomicAdd(&hist[dst[e] >> BIN_SHIFT], 1);
    __syncthreads();
    for (int i = tid; i < nbins; i += 256) {
        int h = hist[i];
        base[i] = h ? atomicAdd(&cursor[i], h) : 0;
        hist[i] = 0;
    }
    __syncthreads();
    for (long long e = e0 + tid; e < e1; e += 256) {
        int d = dst[e];
        int b = d >> BIN_SHIFT;
        int r = atomicAdd(&hist[b], 1);   // re-rank: distinct within (block,bin) is all we need
        binned[base[b] + r] = (int)(((unsigned)(d & (BIN_NODES - 1)) << SRC_BITS) | (unsigned)src[e]);
    }
}

// ---------------- bin scan: binbase = exclscan(cursor[b] - b*CAP) ----------------
__global__ __launch_bounds__(256) void k_binscan(
    const int* __restrict__ cursor, int nbins,
    int* __restrict__ binbase, int* __restrict__ rowptr, int N, int E) {
    __shared__ int wsum[4];
    int tid = threadIdx.x, lane = tid & 63, wid = tid >> 6;
    int b0 = tid * 4;
    int c[4];
#pragma unroll
    for (int k = 0; k < 4; ++k) {
        int b = b0 + k;
        c[k] = (b < nbins) ? cursor[b] - b * BIN_CAP : 0;
    }
    int t = c[0] + c[1] + c[2] + c[3];
    int incl = wave_incl_scan(t, lane);
    if (lane == 63) wsum[wid] = incl;
    __syncthreads();
    int woff = 0;
    for (int w = 0; w < wid; ++w) woff += wsum[w];
    int p = woff + incl - t;
#pragma unroll
    for (int k = 0; k < 4; ++k) {
        int b = b0 + k;
        if (b < nbins) binbase[b] = p;
        p += c[k];
    }
    if (tid == 0) rowptr[N] = E;
}

// ---------------- per-bin sort: csr_src + rowptr + dinv, all LDS-local ----------------
__global__ __launch_bounds__(256) void k_binsort(
    const int* __restrict__ cursor, const int* __restrict__ binbase,
    const int* __restrict__ binned, int N,
    int* __restrict__ csr_src, int* __restrict__ rowptr, float* __restrict__ dinv) {
    __shared__ int cnt[BIN_NODES];
    __shared__ int excl[BIN_NODES];
    __shared__ int rnk[BIN_NODES];
    __shared__ int wsum[2];
    int bin = blockIdx.x;
    int tid = threadIdx.x, lane = tid & 63, wid = tid >> 6;
    int n = cursor[bin] - bin * BIN_CAP;
    int gbase = binbase[bin];
    const int* bp = binned + (size_t)bin * BIN_CAP;
    if (tid < BIN_NODES) { cnt[tid] = 0; rnk[tid] = 0; }
    __syncthreads();
    for (int i = tid; i < n; i += 256)
        atomicAdd(&cnt[((unsigned)bp[i]) >> SRC_BITS], 1);
    __syncthreads();
    int v = (tid < BIN_NODES) ? cnt[tid] : 0;
    int incl = wave_incl_scan(v, lane);
    if (tid < BIN_NODES && lane == 63) wsum[wid] = incl;
    __syncthreads();
    if (tid < BIN_NODES) {
        int off = (wid == 1) ? wsum[0] : 0;
        int ex = off + incl - v;
        excl[tid] = ex;
        int node = bin * BIN_NODES + tid;
        if (node < N) {
            rowptr[node] = gbase + ex;
            dinv[node] = 1.0f / sqrtf((float)v + 1.0f);  // +1 self-loop
        }
    }
    __syncthreads();
    for (int i = tid; i < n; i += 256) {
        unsigned w = (unsigned)bp[i];
        int dl = w >> SRC_BITS;
        int r = atomicAdd(&rnk[dl], 1);
        csr_src[gbase + excl[dl] + r] = (int)(w & SRC_MASK);
    }
}

// ---------------- GEMM: A16 = bf16((f(X) @ W) * dinv), f = relu(.+bias) if RELU_IN ----------------
// 64x64 tile / block, 256 threads, 4x4 register tile / thread, K staged in 64-chunks.
// LDS strides padded to 68 floats: inner-loop b128 reads are 2-way (free, m136).
template<int KTILES, bool RELU_IN>
__global__ __launch_bounds__(256) void k_gemm(
    const float* __restrict__ X, const float* __restrict__ W,
    const float* __restrict__ bias, const float* __restrict__ dinv,
    int N, unsigned short* __restrict__ A16) {
    __shared__ float sX[64][68];
    __shared__ float sW[64][68];
    int tid = threadIdx.x;
    int tx = tid & 15, ty = tid >> 4;
    int row0 = blockIdx.x * 64;
    float acc[4][4] = {};
    // staging coords
    int srow = tid >> 2, scq = (tid & 3) * 16;     // X: 4 threads/row, 16 floats each
    int wrow = tid & 63, wcq = (tid >> 6) * 16;    // W: 64 rows, 4 threads-groups of 16 floats
    for (int kt = 0; kt < KTILES; ++kt) {
        int grow = row0 + srow;
        const float* xp = X + (size_t)grow * (KTILES * 64) + kt * 64 + scq;
#pragma unroll
        for (int i = 0; i < 4; ++i) {
            float4 v = make_float4(0.f, 0.f, 0.f, 0.f);
            if (grow < N) v = *(const float4*)(xp + i * 4);
            if (RELU_IN) {
                const float4 bb = *(const float4*)(bias + kt * 64 + scq + i * 4);
                v.x = fmaxf(v.x + bb.x, 0.f); v.y = fmaxf(v.y + bb.y, 0.f);
                v.z = fmaxf(v.z + bb.z, 0.f); v.w = fmaxf(v.w + bb.w, 0.f);
            }
            *(float4*)&sX[srow][scq + i * 4] = v;
        }
        const float* wp = W + (size_t)(kt * 64 + wrow) * 64 + wcq;
#pragma unroll
        for (int i = 0; i < 4; ++i)
            *(float4*)&sW[wrow][wcq + i * 4] = *(const float4*)(wp + i * 4);
        __syncthreads();
#pragma unroll
        for (int kk = 0; kk < 64; kk += 4) {
            float4 a[4], b[4];
#pragma unroll
            for (int r = 0; r < 4; ++r) a[r] = *(const float4*)&sX[ty * 4 + r][kk];
#pragma unroll
            for (int j = 0; j < 4; ++j) b[j] = *(const float4*)&sW[kk + j][tx * 4];
#pragma unroll
            for (int r = 0; r < 4; ++r) {
                acc[r][0] += a[r].x * b[0].x + a[r].y * b[1].x + a[r].z * b[2].x + a[r].w * b[3].x;
                acc[r][1] += a[r].x * b[0].y + a[r].y * b[1].y + a[r].z * b[2].y + a[r].w * b[3].y;
                acc[r][2] += a[r].x * b[0].z + a[r].y * b[1].z + a[r].z * b[2].z + a[r].w * b[3].z;
                acc[r][3] += a[r].x * b[0].w + a[r].y * b[1].w + a[r].z * b[2].w + a[r].w * b[3].w;
            }
        }
        __syncthreads();
    }
#pragma unroll
    for (int r = 0; r < 4; ++r) {
        int row = row0 + ty * 4 + r;
        if (row < N) {
            float dv = dinv[row];
            ushort4 o;
            o.x = f2bf(acc[r][0] * dv); o.y = f2bf(acc[r][1] * dv);
            o.z = f2bf(acc[r][2] * dv); o.w = f2bf(acc[r][3] * dv);
            *(ushort4*)&A16[(size_t)row * H + tx * 4] = o;
        }
    }
}

// ---------------- gather: row = dinv[n] * (A[n] + sum_{s in in(n)} A[s]),  A in bf16 ----------------
__device__ inline void addbf4(float4& a, ushort4 u) {
    a.x += bf2f(u.x); a.y += bf2f(u.y); a.z += bf2f(u.z); a.w += bf2f(u.w);
}
__device__ inline void add4(float4& a, const float4& b) {
    a.x += b.x; a.y += b.y; a.z += b.z; a.w += b.w;
}

template<bool FUSE>
__global__ __launch_bounds__(256) void k_gather(
    const int* __restrict__ rowptr, const int* __restrict__ csr_src,
    const float* __restrict__ dinv, const unsigned short* __restrict__ A16,
    float* __restrict__ B, int N,
    const float* __restrict__ b2, const float* __restrict__ Wt, const float* __restrict__ bt,
    const float* __restrict__ We, const float* __restrict__ be, float* __restrict__ out) {
    int node = blockIdx.x * 4 + (threadIdx.x >> 6);
    if (node >= N) return;
    int lane = threadIdx.x & 63;
    int grp = lane >> 4, sub = lane & 15;
    const ushort4* A4 = (const ushort4*)A16;     // row = 16 x ushort4
    int beg = rowptr[node], end = rowptr[node + 1];
    float4 a0 = make_float4(0.f, 0.f, 0.f, 0.f), a1 = a0, a2 = a0, a3 = a0;
    if (grp == 0) addbf4(a0, A4[(size_t)node * 16 + sub]);   // self-loop term
    for (int e0 = beg; e0 < end; e0 += 64) {
        int m = end - e0; if (m > 64) m = 64;
        int id = (lane < m) ? csr_src[e0 + lane] : 0;
        int c = 0;
        for (; c + 16 <= m; c += 16) {
            int s0 = __shfl(id, c + grp);
            int s1 = __shfl(id, c + 4 + grp);
            int s2 = __shfl(id, c + 8 + grp);
            int s3 = __shfl(id, c + 12 + grp);
            ushort4 v0 = A4[(size_t)s0 * 16 + sub];
            ushort4 v1 = A4[(size_t)s1 * 16 + sub];
            ushort4 v2 = A4[(size_t)s2 * 16 + sub];
            ushort4 v3 = A4[(size_t)s3 * 16 + sub];
            addbf4(a0, v0); addbf4(a1, v1); addbf4(a2, v2); addbf4(a3, v3);
        }
        for (; c < m; c += 4) {
            int cc = c + grp;
            int s = __shfl(id, cc < m ? cc : 0);
            if (cc < m) addbf4(a0, A4[(size_t)s * 16 + sub]);
        }
    }
    add4(a0, a1); add4(a2, a3); add4(a0, a2);
    a0.x += __shfl_xor(a0.x, 16); a0.y += __shfl_xor(a0.y, 16);
    a0.z += __shfl_xor(a0.z, 16); a0.w += __shfl_xor(a0.w, 16);
    a0.x += __shfl_xor(a0.x, 32); a0.y += __shfl_xor(a0.y, 32);
    a0.z += __shfl_xor(a0.z, 32); a0.w += __shfl_xor(a0.w, 32);
    if (grp == 0) {
        float dv = dinv[node];
        a0.x *= dv; a0.y *= dv; a0.z *= dv; a0.w *= dv;
        if (!FUSE) {
            ((float4*)B)[(size_t)node * 16 + sub] = a0;
        } else {
            int f = sub * 4;
            float g0 = fmaxf(a0.x + b2[f + 0], 0.f);
            float g1 = fmaxf(a0.y + b2[f + 1], 0.f);
            float g2 = fmaxf(a0.z + b2[f + 2], 0.f);
            float g3 = fmaxf(a0.w + b2[f + 3], 0.f);
            float p1 = g0 * Wt[f] + g1 * Wt[f + 1] + g2 * Wt[f + 2] + g3 * Wt[f + 3];
            float p2 = g0 * We[f] + g1 * We[f + 1] + g2 * We[f + 2] + g3 * We[f + 3];
#pragma unroll
            for (int off = 1; off < 16; off <<= 1) {
                p1 += __shfl_xor(p1, off);
                p2 += __shfl_xor(p2, off);
            }
            if (sub == 0) {
                out[node] = p1 + bt[0];
                out[N + node] = p2 + be[0];
            }
        }
    }
}

extern "C" void kernel_launch(void* const* d_in, const int* in_sizes, int n_in,
                              void* d_out, int out_size, void* d_ws, size_t ws_size,
                              hipStream_t stream) {
    const float* x  = (const float*)d_in[0];
    const int* edge = (const int*)d_in[1];
    const float* W1 = (const float*)d_in[2];
    const float* b1 = (const float*)d_in[3];
    const float* W2 = (const float*)d_in[4];
    const float* b2 = (const float*)d_in[5];
    const float* Wt = (const float*)d_in[6];
    const float* bt = (const float*)d_in[7];
    const float* We = (const float*)d_in[8];
    const float* be = (const float*)d_in[9];

    int N = in_sizes[0] / FIN;
    int E = in_sizes[1] / 2;
    const int* src = edge;
    const int* dst = edge + E;
    int nbins = (N + BIN_NODES - 1) >> BIN_SHIFT;

    char* ws = (char*)d_ws;
    size_t off = 0;
    auto alloc = [&](size_t bytes) {
        void* p = ws + off;
        off += (bytes + 255) & ~size_t(255);
        return p;
    };
    float* dinv    = (float*)alloc((size_t)N * sizeof(float));
    int*   rowptr  = (int*)alloc((size_t)(N + 1) * sizeof(int));
    int*   cursor  = (int*)alloc((size_t)nbins * sizeof(int));
    int*   binbase = (int*)alloc((size_t)nbins * sizeof(int));
    int*   binned  = (int*)alloc((size_t)nbins * BIN_CAP * sizeof(int));
    int*   csr_src = (int*)alloc((size_t)E * sizeof(int));
    unsigned short* A16 = (unsigned short*)alloc((size_t)N * H * sizeof(unsigned short));
    float* B       = (float*)alloc((size_t)N * H * sizeof(float));

    // CSR build via two-level bin sort (no per-edge global atomics)
    k_initcur<<<(nbins + 255) / 256, 256, 0, stream>>>(cursor, nbins);
    k_bin<<<512, 256, 0, stream>>>(src, dst, E, nbins, cursor, binned);
    k_binscan<<<1, 256, 0, stream>>>(cursor, nbins, binbase, rowptr, N, E);
    k_binsort<<<nbins, 256, 0, stream>>>(cursor, binbase, binned, N, csr_src, rowptr, dinv);

    int ggrid = (N + 63) / 64;
    // layer 1
    k_gemm<2, false><<<ggrid, 256, 0, stream>>>(x, W1, nullptr, dinv, N, A16);
    k_gather<false><<<(N + 3) / 4, 256, 0, stream>>>(rowptr, csr_src, dinv, A16, B, N,
                                                     nullptr, nullptr, nullptr, nullptr, nullptr, nullptr);

    // layer 2 + fused heads
    k_gemm<1, true><<<ggrid, 256, 0, stream>>>(B, W2, b1, dinv, N, A16);
    k_gather<true><<<(N + 3) / 4, 256, 0, stream>>>(rowptr, csr_src, dinv, A16, nullptr, N,
                                                    b2, Wt, bt, We, be, (float*)d_out);
}

// Round 8
// 234.461 us; speedup vs baseline: 24.2819x; 1.3279x over previous
//
#include <hip/hip_runtime.h>
#include <math.h>

constexpr int H = 64;
constexpr int FIN = 128;
constexpr int BIN_SHIFT = 7;          // 128 nodes per bin
constexpr int BIN_NODES = 1 << BIN_SHIFT;
constexpr int MAX_BINS = 1024;        // supports N <= 131072
constexpr int BIN_CAP = 5120;         // mean 4096 + 16 sigma
constexpr int SRC_BITS = 25;          // word = dstLow7 << 25 | src  (N < 2^25)
constexpr unsigned SRC_MASK = (1u << SRC_BITS) - 1;

typedef __attribute__((ext_vector_type(8))) __bf16 bf16x8;
typedef __attribute__((ext_vector_type(4))) float f32x4;

__device__ inline float bf2f(unsigned short u) {
    unsigned v = ((unsigned)u) << 16;
    return __builtin_bit_cast(float, v);
}
__device__ inline unsigned short f2bf(float f) {
    unsigned u = __builtin_bit_cast(unsigned, f);
    unsigned rnd = 0x7FFFu + ((u >> 16) & 1u);   // RTN-even
    return (unsigned short)((u + rnd) >> 16);
}

__device__ inline int wave_incl_scan(int v, int lane) {
#pragma unroll
    for (int off = 1; off < 64; off <<= 1) {
        int t = __shfl_up(v, off);
        if (lane >= off) v += t;
    }
    return v;
}

// ---------------- cursor init: cursor[b] = b * BIN_CAP ----------------
__global__ void k_initcur(int* __restrict__ cursor, int nbins) {
    int i = blockIdx.x * blockDim.x + threadIdx.x;
    if (i < nbins) cursor[i] = i * BIN_CAP;
}

// ---------------- bin scatter: LDS hist -> run reservation -> packed scatter ----------------
__global__ __launch_bounds__(256) void k_bin(
    const int* __restrict__ src, const int* __restrict__ dst, int E, int nbins,
    int* __restrict__ cursor, int* __restrict__ binned) {
    __shared__ int hist[MAX_BINS];
    __shared__ int base[MAX_BINS];
    int tid = threadIdx.x;
    long long e0 = (long long)E * blockIdx.x / gridDim.x;
    long long e1 = (long long)E * (blockIdx.x + 1) / gridDim.x;
    for (int i = tid; i < nbins; i += 256) hist[i] = 0;
    __syncthreads();
    for (long long e = e0 + tid; e < e1; e += 256)
        atomicAdd(&hist[dst[e] >> BIN_SHIFT], 1);
    __syncthreads();
    for (int i = tid; i < nbins; i += 256) {
        int h = hist[i];
        base[i] = h ? atomicAdd(&cursor[i], h) : 0;
        hist[i] = 0;
    }
    __syncthreads();
    for (long long e = e0 + tid; e < e1; e += 256) {
        int d = dst[e];
        int b = d >> BIN_SHIFT;
        int r = atomicAdd(&hist[b], 1);   // re-rank: distinct within (block,bin) is all we need
        binned[base[b] + r] = (int)(((unsigned)(d & (BIN_NODES - 1)) << SRC_BITS) | (unsigned)src[e]);
    }
}

// ---------------- bin scan: binbase = exclscan(cursor[b] - b*CAP) ----------------
__global__ __launch_bounds__(256) void k_binscan(
    const int* __restrict__ cursor, int nbins,
    int* __restrict__ binbase, int* __restrict__ rowptr, int N, int E) {
    __shared__ int wsum[4];
    int tid = threadIdx.x, lane = tid & 63, wid = tid >> 6;
    int b0 = tid * 4;
    int c[4];
#pragma unroll
    for (int k = 0; k < 4; ++k) {
        int b = b0 + k;
        c[k] = (b < nbins) ? cursor[b] - b * BIN_CAP : 0;
    }
    int t = c[0] + c[1] + c[2] + c[3];
    int incl = wave_incl_scan(t, lane);
    if (lane == 63) wsum[wid] = incl;
    __syncthreads();
    int woff = 0;
    for (int w = 0; w < wid; ++w) woff += wsum[w];
    int p = woff + incl - t;
#pragma unroll
    for (int k = 0; k < 4; ++k) {
        int b = b0 + k;
        if (b < nbins) binbase[b] = p;
        p += c[k];
    }
    if (tid == 0) rowptr[N] = E;
}

// ---------------- per-bin sort: csr_src + rowptr + dinv, all LDS-local ----------------
__global__ __launch_bounds__(256) void k_binsort(
    const int* __restrict__ cursor, const int* __restrict__ binbase,
    const int* __restrict__ binned, int N,
    int* __restrict__ csr_src, int* __restrict__ rowptr, float* __restrict__ dinv) {
    __shared__ int cnt[BIN_NODES];
    __shared__ int excl[BIN_NODES];
    __shared__ int rnk[BIN_NODES];
    __shared__ int wsum[2];
    int bin = blockIdx.x;
    int tid = threadIdx.x, lane = tid & 63, wid = tid >> 6;
    int n = cursor[bin] - bin * BIN_CAP;
    int gbase = binbase[bin];
    const int* bp = binned + (size_t)bin * BIN_CAP;
    if (tid < BIN_NODES) { cnt[tid] = 0; rnk[tid] = 0; }
    __syncthreads();
    for (int i = tid; i < n; i += 256)
        atomicAdd(&cnt[((unsigned)bp[i]) >> SRC_BITS], 1);
    __syncthreads();
    int v = (tid < BIN_NODES) ? cnt[tid] : 0;
    int incl = wave_incl_scan(v, lane);
    if (tid < BIN_NODES && lane == 63) wsum[wid] = incl;
    __syncthreads();
    if (tid < BIN_NODES) {
        int off = (wid == 1) ? wsum[0] : 0;
        int ex = off + incl - v;
        excl[tid] = ex;
        int node = bin * BIN_NODES + tid;
        if (node < N) {
            rowptr[node] = gbase + ex;
            dinv[node] = 1.0f / sqrtf((float)v + 1.0f);  // +1 self-loop
        }
    }
    __syncthreads();
    for (int i = tid; i < n; i += 256) {
        unsigned w = (unsigned)bp[i];
        int dl = w >> SRC_BITS;
        int r = atomicAdd(&rnk[dl], 1);
        csr_src[gbase + excl[dl] + r] = (int)(w & SRC_MASK);
    }
}

// ---------------- MFMA GEMM: A16 = bf16((f(X) @ W) * dinv), f = relu(.+bias) if RELU_IN ----------------
// 64 rows / block, 256 thr = 4 waves; wave w -> 16-row strip, 4 col-tiles of 16.
// X and W^T staged in LDS as bf16 with +8 short padding (fragment b128 reads are 2-way = free).
template<int K, bool RELU_IN>
__global__ __launch_bounds__(256) void k_mgemm(
    const float* __restrict__ X, const float* __restrict__ W,
    const float* __restrict__ bias, const float* __restrict__ dinv,
    int N, unsigned short* __restrict__ A16) {
    constexpr int LDK = K + 8;
    __shared__ short sX[64 * LDK];
    __shared__ short sWt[64 * LDK];
    int tid = threadIdx.x;
    // stage W transposed: sWt[c][k] = bf16(W[k][c])   (coalesced global read)
    for (int idx = tid; idx < K * 64; idx += 256) {
        int k = idx >> 6, c = idx & 63;
        sWt[c * LDK + k] = (short)f2bf(W[idx]);
    }
    // stage X rows as bf16 (optional relu(x+bias)), packed 2-at-a-time
    {
        int row = tid >> 2;
        int q0 = (tid & 3) * (K / 4);
        int grow = blockIdx.x * 64 + row;
        const float* xp = X + (size_t)grow * K + q0;
        unsigned* dstp = (unsigned*)&sX[row * LDK + q0];
#pragma unroll
        for (int i = 0; i < K / 16; ++i) {
            float4 v = make_float4(0.f, 0.f, 0.f, 0.f);
            if (grow < N) v = *(const float4*)(xp + i * 4);
            if (RELU_IN) {
                float4 bb = *(const float4*)(bias + q0 + i * 4);
                v.x = fmaxf(v.x + bb.x, 0.f); v.y = fmaxf(v.y + bb.y, 0.f);
                v.z = fmaxf(v.z + bb.z, 0.f); v.w = fmaxf(v.w + bb.w, 0.f);
            }
            unsigned lo = (unsigned)f2bf(v.x) | ((unsigned)f2bf(v.y) << 16);
            unsigned hi = (unsigned)f2bf(v.z) | ((unsigned)f2bf(v.w) << 16);
            dstp[i * 2] = lo;
            dstp[i * 2 + 1] = hi;
        }
    }
    __syncthreads();
    int w = tid >> 6, lane = tid & 63;
    int mrow = lane & 15, kgrp = lane >> 4;
    f32x4 acc[4] = {};
    const short* xbase = &sX[(16 * w + mrow) * LDK + kgrp * 8];
    const short* wbase = &sWt[mrow * LDK + kgrp * 8];
#pragma unroll
    for (int t = 0; t < K / 32; ++t) {
        bf16x8 a = *(const bf16x8*)(xbase + 32 * t);
#pragma unroll
        for (int c = 0; c < 4; ++c) {
            bf16x8 b = *(const bf16x8*)(wbase + 16 * c * LDK + 32 * t);
            acc[c] = __builtin_amdgcn_mfma_f32_16x16x32_bf16(a, b, acc[c], 0, 0, 0);
        }
    }
    // C/D layout (m89-verified): col = lane&15, row_in_tile = (lane>>4)*4 + reg
    int r0g = blockIdx.x * 64 + 16 * w + kgrp * 4;
#pragma unroll
    for (int r = 0; r < 4; ++r) {
        int rg = r0g + r;
        if (rg < N) {
            float dv = dinv[rg];
#pragma unroll
            for (int c = 0; c < 4; ++c)
                A16[(size_t)rg * H + 16 * c + mrow] = f2bf(acc[c][r] * dv);
        }
    }
}

// ---------------- gather: row = dinv[n] * (A[n] + sum_{s in in(n)} A[s]),  A in bf16 ----------------
__device__ inline void addbf4(float4& a, ushort4 u) {
    a.x += bf2f(u.x); a.y += bf2f(u.y); a.z += bf2f(u.z); a.w += bf2f(u.w);
}
__device__ inline void add4(float4& a, const float4& b) {
    a.x += b.x; a.y += b.y; a.z += b.z; a.w += b.w;
}

template<bool FUSE>
__global__ __launch_bounds__(256) void k_gather(
    const int* __restrict__ rowptr, const int* __restrict__ csr_src,
    const float* __restrict__ dinv, const unsigned short* __restrict__ A16,
    float* __restrict__ B, int N,
    const float* __restrict__ b2, const float* __restrict__ Wt, const float* __restrict__ bt,
    const float* __restrict__ We, const float* __restrict__ be, float* __restrict__ out) {
    int node = blockIdx.x * 4 + (threadIdx.x >> 6);
    if (node >= N) return;
    int lane = threadIdx.x & 63;
    int grp = lane >> 4, sub = lane & 15;
    const ushort4* A4 = (const ushort4*)A16;     // row = 16 x ushort4
    int beg = rowptr[node], end = rowptr[node + 1];
    float4 a0 = make_float4(0.f, 0.f, 0.f, 0.f), a1 = a0, a2 = a0, a3 = a0;
    if (grp == 0) addbf4(a0, A4[(size_t)node * 16 + sub]);   // self-loop term
    for (int e0 = beg; e0 < end; e0 += 64) {
        int m = end - e0; if (m > 64) m = 64;
        int id = (lane < m) ? csr_src[e0 + lane] : 0;
        int c = 0;
        for (; c + 16 <= m; c += 16) {
            int s0 = __shfl(id, c + grp);
            int s1 = __shfl(id, c + 4 + grp);
            int s2 = __shfl(id, c + 8 + grp);
            int s3 = __shfl(id, c + 12 + grp);
            ushort4 v0 = A4[(size_t)s0 * 16 + sub];
            ushort4 v1 = A4[(size_t)s1 * 16 + sub];
            ushort4 v2 = A4[(size_t)s2 * 16 + sub];
            ushort4 v3 = A4[(size_t)s3 * 16 + sub];
            addbf4(a0, v0); addbf4(a1, v1); addbf4(a2, v2); addbf4(a3, v3);
        }
        for (; c < m; c += 4) {
            int cc = c + grp;
            int s = __shfl(id, cc < m ? cc : 0);
            if (cc < m) addbf4(a0, A4[(size_t)s * 16 + sub]);
        }
    }
    add4(a0, a1); add4(a2, a3); add4(a0, a2);
    a0.x += __shfl_xor(a0.x, 16); a0.y += __shfl_xor(a0.y, 16);
    a0.z += __shfl_xor(a0.z, 16); a0.w += __shfl_xor(a0.w, 16);
    a0.x += __shfl_xor(a0.x, 32); a0.y += __shfl_xor(a0.y, 32);
    a0.z += __shfl_xor(a0.z, 32); a0.w += __shfl_xor(a0.w, 32);
    if (grp == 0) {
        float dv = dinv[node];
        a0.x *= dv; a0.y *= dv; a0.z *= dv; a0.w *= dv;
        if (!FUSE) {
            ((float4*)B)[(size_t)node * 16 + sub] = a0;
        } else {
            int f = sub * 4;
            float g0 = fmaxf(a0.x + b2[f + 0], 0.f);
            float g1 = fmaxf(a0.y + b2[f + 1], 0.f);
            float g2 = fmaxf(a0.z + b2[f + 2], 0.f);
            float g3 = fmaxf(a0.w + b2[f + 3], 0.f);
            float p1 = g0 * Wt[f] + g1 * Wt[f + 1] + g2 * Wt[f + 2] + g3 * Wt[f + 3];
            float p2 = g0 * We[f] + g1 * We[f + 1] + g2 * We[f + 2] + g3 * We[f + 3];
#pragma unroll
            for (int off = 1; off < 16; off <<= 1) {
                p1 += __shfl_xor(p1, off);
                p2 += __shfl_xor(p2, off);
            }
            if (sub == 0) {
                out[node] = p1 + bt[0];
                out[N + node] = p2 + be[0];
            }
        }
    }
}

extern "C" void kernel_launch(void* const* d_in, const int* in_sizes, int n_in,
                              void* d_out, int out_size, void* d_ws, size_t ws_size,
                              hipStream_t stream) {
    const float* x  = (const float*)d_in[0];
    const int* edge = (const int*)d_in[1];
    const float* W1 = (const float*)d_in[2];
    const float* b1 = (const float*)d_in[3];
    const float* W2 = (const float*)d_in[4];
    const float* b2 = (const float*)d_in[5];
    const float* Wt = (const float*)d_in[6];
    const float* bt = (const float*)d_in[7];
    const float* We = (const float*)d_in[8];
    const float* be = (const float*)d_in[9];

    int N = in_sizes[0] / FIN;
    int E = in_sizes[1] / 2;
    const int* src = edge;
    const int* dst = edge + E;
    int nbins = (N + BIN_NODES - 1) >> BIN_SHIFT;

    char* ws = (char*)d_ws;
    size_t off = 0;
    auto alloc = [&](size_t bytes) {
        void* p = ws + off;
        off += (bytes + 255) & ~size_t(255);
        return p;
    };
    float* dinv    = (float*)alloc((size_t)N * sizeof(float));
    int*   rowptr  = (int*)alloc((size_t)(N + 1) * sizeof(int));
    int*   cursor  = (int*)alloc((size_t)nbins * sizeof(int));
    int*   binbase = (int*)alloc((size_t)nbins * sizeof(int));
    int*   binned  = (int*)alloc((size_t)nbins * BIN_CAP * sizeof(int));
    int*   csr_src = (int*)alloc((size_t)E * sizeof(int));
    unsigned short* A16 = (unsigned short*)alloc((size_t)N * H * sizeof(unsigned short));
    float* B       = (float*)alloc((size_t)N * H * sizeof(float));

    // CSR build via two-level bin sort (no per-edge global atomics)
    k_initcur<<<(nbins + 255) / 256, 256, 0, stream>>>(cursor, nbins);
    k_bin<<<512, 256, 0, stream>>>(src, dst, E, nbins, cursor, binned);
    k_binscan<<<1, 256, 0, stream>>>(cursor, nbins, binbase, rowptr, N, E);
    k_binsort<<<nbins, 256, 0, stream>>>(cursor, binbase, binned, N, csr_src, rowptr, dinv);

    int ggrid = (N + 63) / 64;
    // layer 1
    k_mgemm<FIN, false><<<ggrid, 256, 0, stream>>>(x, W1, nullptr, dinv, N, A16);
    k_gather<false><<<(N + 3) / 4, 256, 0, stream>>>(rowptr, csr_src, dinv, A16, B, N,
                                                     nullptr, nullptr, nullptr, nullptr, nullptr, nullptr);

    // layer 2 + fused heads
    k_mgemm<H, true><<<ggrid, 256, 0, stream>>>(B, W2, b1, dinv, N, A16);
    k_gather<true><<<(N + 3) / 4, 256, 0, stream>>>(rowptr, csr_src, dinv, A16, nullptr, N,
                                                    b2, Wt, bt, We, be, (float*)d_out);
}

// Round 9
// 226.316 us; speedup vs baseline: 25.1558x; 1.0360x over previous
//
#include <hip/hip_runtime.h>
#include <math.h>

constexpr int H = 64;
constexpr int FIN = 128;
constexpr int BIN_SHIFT = 8;          // 256 nodes per bin
constexpr int BIN_NODES = 1 << BIN_SHIFT;
constexpr int MAX_BINS = 512;         // supports N <= 131072
constexpr int BIN_CAP = 10240;        // mean 8192 + ~22 sigma
constexpr int SRC_BITS = 24;          // word = dstLow8 << 24 | src  (N < 2^24)
constexpr unsigned SRC_MASK = (1u << SRC_BITS) - 1;
constexpr int KB_BLOCKS = 512;
constexpr int KB_ITER = 25;           // fast path covers E <= 512*256*25 = 3.276M

typedef __attribute__((ext_vector_type(8))) __bf16 bf16x8;
typedef __attribute__((ext_vector_type(4))) float f32x4;

__device__ inline float bf2f(unsigned short u) {
    unsigned v = ((unsigned)u) << 16;
    return __builtin_bit_cast(float, v);
}
__device__ inline unsigned short f2bf(float f) {
    unsigned u = __builtin_bit_cast(unsigned, f);
    unsigned rnd = 0x7FFFu + ((u >> 16) & 1u);   // RTN-even
    return (unsigned short)((u + rnd) >> 16);
}

__device__ inline int wave_incl_scan(int v, int lane) {
#pragma unroll
    for (int off = 1; off < 64; off <<= 1) {
        int t = __shfl_up(v, off);
        if (lane >= off) v += t;
    }
    return v;
}

// ---------------- cursor init: cursor[b] = b * BIN_CAP ----------------
__global__ void k_initcur(int* __restrict__ cursor, int nbins) {
    int i = blockIdx.x * blockDim.x + threadIdx.x;
    if (i < nbins) cursor[i] = i * BIN_CAP;
}

// ---------------- bin scatter: LDS hist w/ register-carried rank -> run reservation -> packed scatter ----------------
__global__ __launch_bounds__(256) void k_bin(
    const int* __restrict__ src, const int* __restrict__ dst, int E, int nbins,
    int* __restrict__ cursor, int* __restrict__ binned) {
    __shared__ int hist[MAX_BINS];
    __shared__ int base[MAX_BINS];
    int tid = threadIdx.x;
    long long e0 = (long long)E * blockIdx.x / gridDim.x;
    long long e1 = (long long)E * (blockIdx.x + 1) / gridDim.x;
    int chunk = (int)(e1 - e0);
    for (int i = tid; i < nbins; i += 256) hist[i] = 0;
    __syncthreads();
    // phase 1: count + keep (bin, dstLow, rank) in registers.  [b:10][dl:8][r:14]
    int packed[KB_ITER];
#pragma unroll
    for (int i = 0; i < KB_ITER; ++i) {
        int o = i * 256 + tid;
        packed[i] = -1;
        if (o < chunk) {
            int d = dst[e0 + o];
            int b = d >> BIN_SHIFT;
            int r = atomicAdd(&hist[b], 1);   // r < chunk <= 6400 < 2^14
            packed[i] = (b << 22) | ((d & (BIN_NODES - 1)) << 14) | r;
        }
    }
    __syncthreads();
    // phase 1.5: reserve a contiguous run per (block,bin)
    for (int i = tid; i < nbins; i += 256) {
        int h = hist[i];
        base[i] = h ? atomicAdd(&cursor[i], h) : 0;
    }
    __syncthreads();
    // phase 2: atomic-free scatter, src read once, dst never re-read
#pragma unroll
    for (int i = 0; i < KB_ITER; ++i) {
        int o = i * 256 + tid;
        if (o < chunk) {
            unsigned w = (unsigned)packed[i];
            int b = (int)(w >> 22);
            int dl = (int)((w >> 14) & 0xFF);
            int r = (int)(w & 0x3FFF);
            binned[base[b] + r] = (int)(((unsigned)dl << SRC_BITS) | (unsigned)src[e0 + o]);
        }
    }
    // slow-path tail (only if chunk > KB_ITER*256; empty for E=3.2M)
    for (int o = KB_ITER * 256 + tid; o < chunk; o += 256) {
        int d = dst[e0 + o];
        int b = d >> BIN_SHIFT;
        int r = atomicAdd(&cursor[b], 1);
        binned[r] = (int)(((unsigned)(d & (BIN_NODES - 1)) << SRC_BITS) | (unsigned)src[e0 + o]);
    }
}

// ---------------- bin scan: binbase = exclscan(cursor[b] - b*CAP) ----------------
__global__ __launch_bounds__(256) void k_binscan(
    const int* __restrict__ cursor, int nbins,
    int* __restrict__ binbase, int* __restrict__ rowptr, int N, int E) {
    __shared__ int wsum[4];
    int tid = threadIdx.x, lane = tid & 63, wid = tid >> 6;
    int b0 = tid * 4;
    int c[4];
#pragma unroll
    for (int k = 0; k < 4; ++k) {
        int b = b0 + k;
        c[k] = (b < nbins) ? cursor[b] - b * BIN_CAP : 0;
    }
    int t = c[0] + c[1] + c[2] + c[3];
    int incl = wave_incl_scan(t, lane);
    if (lane == 63) wsum[wid] = incl;
    __syncthreads();
    int woff = 0;
    for (int w = 0; w < wid; ++w) woff += wsum[w];
    int p = woff + incl - t;
#pragma unroll
    for (int k = 0; k < 4; ++k) {
        int b = b0 + k;
        if (b < nbins) binbase[b] = p;
        p += c[k];
    }
    if (tid == 0) rowptr[N] = E;
}

// ---------------- per-bin sort: csr_src + rowptr + dinv, all LDS-local ----------------
__global__ __launch_bounds__(256) void k_binsort(
    const int* __restrict__ cursor, const int* __restrict__ binbase,
    const int* __restrict__ binned, int N,
    int* __restrict__ csr_src, int* __restrict__ rowptr, float* __restrict__ dinv) {
    __shared__ int cnt[BIN_NODES];
    __shared__ int excl[BIN_NODES];
    __shared__ int rnk[BIN_NODES];
    __shared__ int wsum[4];
    int bin = blockIdx.x;
    int tid = threadIdx.x, lane = tid & 63, wid = tid >> 6;
    int n = cursor[bin] - bin * BIN_CAP;
    int gbase = binbase[bin];
    const int* bp = binned + (size_t)bin * BIN_CAP;
    cnt[tid] = 0; rnk[tid] = 0;
    __syncthreads();
    for (int i = tid; i < n; i += 256)
        atomicAdd(&cnt[((unsigned)bp[i]) >> SRC_BITS], 1);
    __syncthreads();
    int v = cnt[tid];
    int incl = wave_incl_scan(v, lane);
    if (lane == 63) wsum[wid] = incl;
    __syncthreads();
    int woff = 0;
    for (int w = 0; w < wid; ++w) woff += wsum[w];
    int ex = woff + incl - v;
    excl[tid] = ex;
    int node = bin * BIN_NODES + tid;
    if (node < N) {
        rowptr[node] = gbase + ex;
        dinv[node] = 1.0f / sqrtf((float)v + 1.0f);  // +1 self-loop
    }
    __syncthreads();
    for (int i = tid; i < n; i += 256) {
        unsigned w = (unsigned)bp[i];
        int dl = w >> SRC_BITS;
        int r = atomicAdd(&rnk[dl], 1);
        csr_src[gbase + excl[dl] + r] = (int)(w & SRC_MASK);
    }
}

// ---------------- MFMA GEMM: A16 = bf16((f(X) @ W) * dinv), f = relu(.+bias) if RELU_IN ----------------
// 64 rows / block, 256 thr = 4 waves; wave w -> 16-row strip, 4 col-tiles of 16.
// X and W^T staged in LDS as bf16 with +8 short padding (fragment b128 reads are 2-way = free).
template<int K, bool RELU_IN>
__global__ __launch_bounds__(256) void k_mgemm(
    const float* __restrict__ X, const float* __restrict__ W,
    const float* __restrict__ bias, const float* __restrict__ dinv,
    int N, unsigned short* __restrict__ A16) {
    constexpr int LDK = K + 8;
    __shared__ short sX[64 * LDK];
    __shared__ short sWt[64 * LDK];
    int tid = threadIdx.x;
    // stage W transposed: sWt[c][k] = bf16(W[k][c])   (coalesced global read)
    for (int idx = tid; idx < K * 64; idx += 256) {
        int k = idx >> 6, c = idx & 63;
        sWt[c * LDK + k] = (short)f2bf(W[idx]);
    }
    // stage X rows as bf16 (optional relu(x+bias)), packed 2-at-a-time
    {
        int row = tid >> 2;
        int q0 = (tid & 3) * (K / 4);
        int grow = blockIdx.x * 64 + row;
        const float* xp = X + (size_t)grow * K + q0;
        unsigned* dstp = (unsigned*)&sX[row * LDK + q0];
#pragma unroll
        for (int i = 0; i < K / 16; ++i) {
            float4 v = make_float4(0.f, 0.f, 0.f, 0.f);
            if (grow < N) v = *(const float4*)(xp + i * 4);
            if (RELU_IN) {
                float4 bb = *(const float4*)(bias + q0 + i * 4);
                v.x = fmaxf(v.x + bb.x, 0.f); v.y = fmaxf(v.y + bb.y, 0.f);
                v.z = fmaxf(v.z + bb.z, 0.f); v.w = fmaxf(v.w + bb.w, 0.f);
            }
            unsigned lo = (unsigned)f2bf(v.x) | ((unsigned)f2bf(v.y) << 16);
            unsigned hi = (unsigned)f2bf(v.z) | ((unsigned)f2bf(v.w) << 16);
            dstp[i * 2] = lo;
            dstp[i * 2 + 1] = hi;
        }
    }
    __syncthreads();
    int w = tid >> 6, lane = tid & 63;
    int mrow = lane & 15, kgrp = lane >> 4;
    f32x4 acc[4] = {};
    const short* xbase = &sX[(16 * w + mrow) * LDK + kgrp * 8];
    const short* wbase = &sWt[mrow * LDK + kgrp * 8];
#pragma unroll
    for (int t = 0; t < K / 32; ++t) {
        bf16x8 a = *(const bf16x8*)(xbase + 32 * t);
#pragma unroll
        for (int c = 0; c < 4; ++c) {
            bf16x8 b = *(const bf16x8*)(wbase + 16 * c * LDK + 32 * t);
            acc[c] = __builtin_amdgcn_mfma_f32_16x16x32_bf16(a, b, acc[c], 0, 0, 0);
        }
    }
    // C/D layout (m89-verified): col = lane&15, row_in_tile = (lane>>4)*4 + reg
    int r0g = blockIdx.x * 64 + 16 * w + kgrp * 4;
#pragma unroll
    for (int r = 0; r < 4; ++r) {
        int rg = r0g + r;
        if (rg < N) {
            float dv = dinv[rg];
#pragma unroll
            for (int c = 0; c < 4; ++c)
                A16[(size_t)rg * H + 16 * c + mrow] = f2bf(acc[c][r] * dv);
        }
    }
}

// ---------------- gather: row = dinv[n] * (A[n] + sum_{s in in(n)} A[s]),  A in bf16 ----------------
__device__ inline void addbf4(float4& a, ushort4 u) {
    a.x += bf2f(u.x); a.y += bf2f(u.y); a.z += bf2f(u.z); a.w += bf2f(u.w);
}
__device__ inline void add4(float4& a, const float4& b) {
    a.x += b.x; a.y += b.y; a.z += b.z; a.w += b.w;
}

template<bool FUSE>
__global__ __launch_bounds__(256) void k_gather(
    const int* __restrict__ rowptr, const int* __restrict__ csr_src,
    const float* __restrict__ dinv, const unsigned short* __restrict__ A16,
    float* __restrict__ B, int N,
    const float* __restrict__ b2, const float* __restrict__ Wt, const float* __restrict__ bt,
    const float* __restrict__ We, const float* __restrict__ be, float* __restrict__ out) {
    int node = blockIdx.x * 4 + (threadIdx.x >> 6);
    if (node >= N) return;
    int lane = threadIdx.x & 63;
    int grp = lane >> 4, sub = lane & 15;
    const ushort4* A4 = (const ushort4*)A16;     // row = 16 x ushort4
    int beg = rowptr[node], end = rowptr[node + 1];
    float4 a0 = make_float4(0.f, 0.f, 0.f, 0.f), a1 = a0, a2 = a0, a3 = a0;
    if (grp == 0) addbf4(a0, A4[(size_t)node * 16 + sub]);   // self-loop term
    for (int e0 = beg; e0 < end; e0 += 64) {
        int m = end - e0; if (m > 64) m = 64;
        int id = (lane < m) ? csr_src[e0 + lane] : 0;
        int c = 0;
        for (; c + 16 <= m; c += 16) {
            int s0 = __shfl(id, c + grp);
            int s1 = __shfl(id, c + 4 + grp);
            int s2 = __shfl(id, c + 8 + grp);
            int s3 = __shfl(id, c + 12 + grp);
            ushort4 v0 = A4[(size_t)s0 * 16 + sub];
            ushort4 v1 = A4[(size_t)s1 * 16 + sub];
            ushort4 v2 = A4[(size_t)s2 * 16 + sub];
            ushort4 v3 = A4[(size_t)s3 * 16 + sub];
            addbf4(a0, v0); addbf4(a1, v1); addbf4(a2, v2); addbf4(a3, v3);
        }
        for (; c < m; c += 4) {
            int cc = c + grp;
            int s = __shfl(id, cc < m ? cc : 0);
            if (cc < m) addbf4(a0, A4[(size_t)s * 16 + sub]);
        }
    }
    add4(a0, a1); add4(a2, a3); add4(a0, a2);
    a0.x += __shfl_xor(a0.x, 16); a0.y += __shfl_xor(a0.y, 16);
    a0.z += __shfl_xor(a0.z, 16); a0.w += __shfl_xor(a0.w, 16);
    a0.x += __shfl_xor(a0.x, 32); a0.y += __shfl_xor(a0.y, 32);
    a0.z += __shfl_xor(a0.z, 32); a0.w += __shfl_xor(a0.w, 32);
    if (grp == 0) {
        float dv = dinv[node];
        a0.x *= dv; a0.y *= dv; a0.z *= dv; a0.w *= dv;
        if (!FUSE) {
            ((float4*)B)[(size_t)node * 16 + sub] = a0;
        } else {
            int f = sub * 4;
            float g0 = fmaxf(a0.x + b2[f + 0], 0.f);
            float g1 = fmaxf(a0.y + b2[f + 1], 0.f);
            float g2 = fmaxf(a0.z + b2[f + 2], 0.f);
            float g3 = fmaxf(a0.w + b2[f + 3], 0.f);
            float p1 = g0 * Wt[f] + g1 * Wt[f + 1] + g2 * Wt[f + 2] + g3 * Wt[f + 3];
            float p2 = g0 * We[f] + g1 * We[f + 1] + g2 * We[f + 2] + g3 * We[f + 3];
#pragma unroll
            for (int off = 1; off < 16; off <<= 1) {
                p1 += __shfl_xor(p1, off);
                p2 += __shfl_xor(p2, off);
            }
            if (sub == 0) {
                out[node] = p1 + bt[0];
                out[N + node] = p2 + be[0];
            }
        }
    }
}

extern "C" void kernel_launch(void* const* d_in, const int* in_sizes, int n_in,
                              void* d_out, int out_size, void* d_ws, size_t ws_size,
                              hipStream_t stream) {
    const float* x  = (const float*)d_in[0];
    const int* edge = (const int*)d_in[1];
    const float* W1 = (const float*)d_in[2];
    const float* b1 = (const float*)d_in[3];
    const float* W2 = (const float*)d_in[4];
    const float* b2 = (const float*)d_in[5];
    const float* Wt = (const float*)d_in[6];
    const float* bt = (const float*)d_in[7];
    const float* We = (const float*)d_in[8];
    const float* be = (const float*)d_in[9];

    int N = in_sizes[0] / FIN;
    int E = in_sizes[1] / 2;
    const int* src = edge;
    const int* dst = edge + E;
    int nbins = (N + BIN_NODES - 1) >> BIN_SHIFT;

    char* ws = (char*)d_ws;
    size_t off = 0;
    auto alloc = [&](size_t bytes) {
        void* p = ws + off;
        off += (bytes + 255) & ~size_t(255);
        return p;
    };
    float* dinv    = (float*)alloc((size_t)N * sizeof(float));
    int*   rowptr  = (int*)alloc((size_t)(N + 1) * sizeof(int));
    int*   cursor  = (int*)alloc((size_t)nbins * sizeof(int));
    int*   binbase = (int*)alloc((size_t)nbins * sizeof(int));
    int*   binned  = (int*)alloc((size_t)nbins * BIN_CAP * sizeof(int));
    int*   csr_src = (int*)alloc((size_t)E * sizeof(int));
    unsigned short* A16 = (unsigned short*)alloc((size_t)N * H * sizeof(unsigned short));
    float* B       = (float*)alloc((size_t)N * H * sizeof(float));

    // CSR build via two-level bin sort (no per-edge global atomics)
    k_initcur<<<(nbins + 255) / 256, 256, 0, stream>>>(cursor, nbins);
    k_bin<<<KB_BLOCKS, 256, 0, stream>>>(src, dst, E, nbins, cursor, binned);
    k_binscan<<<1, 256, 0, stream>>>(cursor, nbins, binbase, rowptr, N, E);
    k_binsort<<<nbins, 256, 0, stream>>>(cursor, binbase, binned, N, csr_src, rowptr, dinv);

    int ggrid = (N + 63) / 64;
    // layer 1
    k_mgemm<FIN, false><<<ggrid, 256, 0, stream>>>(x, W1, nullptr, dinv, N, A16);
    k_gather<false><<<(N + 3) / 4, 256, 0, stream>>>(rowptr, csr_src, dinv, A16, B, N,
                                                     nullptr, nullptr, nullptr, nullptr, nullptr, nullptr);

    // layer 2 + fused heads
    k_mgemm<H, true><<<ggrid, 256, 0, stream>>>(B, W2, b1, dinv, N, A16);
    k_gather<true><<<(N + 3) / 4, 256, 0, stream>>>(rowptr, csr_src, dinv, A16, nullptr, N,
                                                    b2, Wt, bt, We, be, (float*)d_out);
}